// Round 1
// baseline (39614.120 us; speedup 1.0000x reference)
//
#include <hip/hip_runtime.h>
#include <hip/hip_cooperative_groups.h>
#include <hip/hip_bf16.h>
#include <math.h>

namespace cg = cooperative_groups;

#define BDIM 512
#define TDIM 1024
#define UDIM 512
#define NG   2048   // 4*U

typedef __attribute__((ext_vector_type(8))) short short8;
typedef __attribute__((ext_vector_type(4))) float float4v;

// ---------------- workspace layout ----------------
#define OFF_U0T   ((size_t)0)                       // bf16 [2048][512]  gate-interleaved, transposed
#define SZ_U0T    ((size_t)NG*UDIM*2)
#define OFF_W1U1T (OFF_U0T + SZ_U0T)                // bf16 [2048][1024] (W1 rows 0-511, U1 rows 512-1023)
#define SZ_W1U1T  ((size_t)NG*1024*2)
#define OFF_W0P   (OFF_W1U1T + SZ_W1U1T)            // f32 [3][2048] permuted
#define SZ_W0P    ((size_t)3*NG*4)
#define OFF_B0P   (OFF_W0P + SZ_W0P)                // f32 [2048] permuted
#define OFF_B1P   (OFF_B0P + (size_t)NG*4)
#define OFF_STATE (OFF_B1P + (size_t)NG*4)
#define SZ_HB     ((size_t)BDIM*UDIM*2)
#define SZ_HF     ((size_t)BDIM*UDIM*4)
#define OFF_H0B   (OFF_STATE)                       // bf16 x2 (ping-pong)
#define OFF_H1B   (OFF_H0B + 2*SZ_HB)
#define OFF_H0F   (OFF_H1B + 2*SZ_HB)               // f32 master x2
#define OFF_H1F   (OFF_H0F + 2*SZ_HF)
#define OFF_C0    (OFF_H1F + 2*SZ_HF)               // f32 in-place
#define OFF_C1    (OFF_C0 + SZ_HF)
#define STATE_BYTES (OFF_C1 + SZ_HF - OFF_STATE)    // 8 MB exactly

// LDS: two staging buffers (A 10240B + B 10240B each) = 40960B; epilogue Z aliases.
#define BUF_BYTES 20480

__device__ __forceinline__ float sigm(float x) { return 1.0f / (1.0f + expf(-x)); }

// Weight prep: bf16 convert + transpose to [n',k] + gate-interleave columns
// n' = unit*4 + gate  <-  orig col = gate*512 + unit
__global__ void prep_kernel(const float* __restrict__ W0, const float* __restrict__ U0,
                            const float* __restrict__ b0, const float* __restrict__ W1,
                            const float* __restrict__ U1, const float* __restrict__ b1,
                            char* __restrict__ ws)
{
    int idx = blockIdx.x * 256 + threadIdx.x;   // 2048*1024 total
    int n = idx >> 10;
    int k = idx & 1023;
    int oc = (n & 3) * UDIM + (n >> 2);
    __hip_bfloat16* U0t = (__hip_bfloat16*)(ws + OFF_U0T);
    __hip_bfloat16* Wc  = (__hip_bfloat16*)(ws + OFF_W1U1T);
    float* W0p = (float*)(ws + OFF_W0P);
    float* b0p = (float*)(ws + OFF_B0P);
    float* b1p = (float*)(ws + OFF_B1P);
    if (k < 512) U0t[(size_t)n * 512 + k] = __float2bfloat16(U0[(size_t)k * NG + oc]);
    float wv = (k < 512) ? W1[(size_t)k * NG + oc] : U1[(size_t)(k - 512) * NG + oc];
    Wc[(size_t)n * 1024 + k] = __float2bfloat16(wv);
    if (k < 3) W0p[k * NG + n] = W0[(size_t)k * NG + oc];
    if (k == 0) { b0p[n] = b0[oc]; b1p[n] = b1[oc]; }
}

// ---- k-loop helpers (static register names, no dynamic indexing) ----
__device__ __forceinline__ void tile_load(int itile,
    const __hip_bfloat16* __restrict__ Aa, const __hip_bfloat16* __restrict__ Ab,
    const __hip_bfloat16* __restrict__ Wt, int KTOT, int mtile, int ntile,
    int sr, int sq, short8& ra, short8& rb)
{
    int kc = itile * 32;
    const __hip_bfloat16* Ap = (kc < 512) ? Aa : Ab;
    ra = *(const short8*)(Ap + (size_t)(mtile * 128 + sr) * UDIM + (kc & 511) + sq * 8);
    rb = *(const short8*)(Wt + (size_t)(ntile * 128 + sr) * KTOT + kc + sq * 8);
}

__device__ __forceinline__ void tile_store(char* smem, int bufidx, int sr, int sq,
                                           short8 ra, short8 rb)
{
    short* dA = (short*)(smem + bufidx * BUF_BYTES);
    *(short8*)&dA[sr * 40 + sq * 8] = ra;
    *(short8*)&dA[5120 + sr * 40 + sq * 8] = rb;
}

__device__ __forceinline__ void frag_mma(const char* smem, int bufidx,
                                         int wr, int wc, int lr, int lq,
                                         float4v (&acc)[4][2])
{
    const short* sA = (const short*)(smem + bufidx * BUF_BYTES);
    const short* sB = sA + 5120;
    short8 aF[4], bF[2];
#pragma unroll
    for (int i = 0; i < 4; ++i) aF[i] = *(const short8*)&sA[(wr + i * 16 + lr) * 40 + lq * 8];
#pragma unroll
    for (int j = 0; j < 2; ++j) bF[j] = *(const short8*)&sB[(wc + j * 16 + lr) * 40 + lq * 8];
#pragma unroll
    for (int i = 0; i < 4; ++i)
#pragma unroll
        for (int j = 0; j < 2; ++j)
            acc[i][j] = __builtin_amdgcn_mfma_f32_16x16x32_bf16(aF[i], bF[j], acc[i][j], 0, 0, 0);
}

// One LSTM-cell 128x128 output tile: bf16 MFMA GEMM + fused gate/time-gate epilogue.
// 512 threads / 8 waves: wave w -> rows (w&1)*64, perm-cols (w>>1)*32 (4x2 fragments).
// Single-sync double-buffered k-loop, depth-2 register prefetch.
__device__ void cell_tile(
    char* smem, int tile, int t, int KTOT,
    const __hip_bfloat16* __restrict__ Aa, const __hip_bfloat16* __restrict__ Ab,
    const __hip_bfloat16* __restrict__ Wt,
    const float* __restrict__ bias, const float* __restrict__ W0p,
    const float* __restrict__ inputs, const float* __restrict__ times,
    const float* __restrict__ tau, const float* __restrict__ sph,
    float* __restrict__ cst,
    const float* __restrict__ hf_prev, float* __restrict__ hf_cur,
    __hip_bfloat16* __restrict__ hb_cur)
{
    const int tid = threadIdx.x;
    const int mtile = tile >> 4;     // 0..3  (rows mtile*128)
    const int ntile = tile & 15;     // 0..15 (perm cols ntile*128 = units ntile*32..+31)
    const int wave = tid >> 6, lane = tid & 63;
    const int wr = (wave & 1) * 64, wc = (wave >> 1) * 32;
    const int lr = lane & 15, lq = lane >> 4;
    const int sr = tid >> 2, sq = tid & 3;    // staging: row 0..127, 16B quad 0..3

    const float4v zero4 = {0.0f, 0.0f, 0.0f, 0.0f};
    float4v acc[4][2];
#pragma unroll
    for (int i = 0; i < 4; ++i)
#pragma unroll
        for (int j = 0; j < 2; ++j) acc[i][j] = zero4;

    const int NIT = KTOT >> 5;                // 16 or 32, always even
    short8 a0, b0r, a1, b1r;
    tile_load(0, Aa, Ab, Wt, KTOT, mtile, ntile, sr, sq, a0, b0r);
    tile_store(smem, 0, sr, sq, a0, b0r);
    tile_load(1, Aa, Ab, Wt, KTOT, mtile, ntile, sr, sq, a1, b1r);
    __syncthreads();
    for (int it = 0; it < NIT; it += 2) {
        // even half: consume buf0 (tile it), prefetch tile it+2 into set0, commit tile it+1
        if (it + 2 < NIT) tile_load(it + 2, Aa, Ab, Wt, KTOT, mtile, ntile, sr, sq, a0, b0r);
        frag_mma(smem, 0, wr, wc, lr, lq, acc);
        tile_store(smem, 1, sr, sq, a1, b1r);
        __syncthreads();
        // odd half: consume buf1 (tile it+1), prefetch tile it+3 into set1, commit tile it+2
        if (it + 3 < NIT) tile_load(it + 3, Aa, Ab, Wt, KTOT, mtile, ntile, sr, sq, a1, b1r);
        frag_mma(smem, 1, wr, wc, lr, lq, acc);
        if (it + 2 < NIT) tile_store(smem, 0, sr, sq, a0, b0r);
        __syncthreads();
    }

    // Epilogue: two col-halves (units ch*16..+15 of this tile) through LDS.
    float* Z = (float*)smem;   // [128][68] f32 (aliases staging buffers)
    for (int ch = 0; ch < 2; ++ch) {
        __syncthreads();
        if ((wc >> 6) == ch) {
#pragma unroll
            for (int i = 0; i < 4; ++i)
#pragma unroll
                for (int j = 0; j < 2; ++j)
#pragma unroll
                    for (int r = 0; r < 4; ++r)
                        Z[(wr + i * 16 + lq * 4 + r) * 68 + ((wc & 63) + j * 16 + lr)] = acc[i][j][r];
        }
        __syncthreads();
        for (int rep = 0; rep < 4; ++rep) {
            int p = rep * 512 + tid;
            int row = p >> 4, ul = p & 15;
            float4v z = *(const float4v*)&Z[row * 68 + ul * 4];
            int b = mtile * 128 + row;
            int u = ntile * 32 + ch * 16 + ul;
            int pc = u * 4;
            float zi = z[0] + bias[pc + 0];
            float zf = z[1] + bias[pc + 1];
            float zg = z[2] + bias[pc + 2];
            float zo = z[3] + bias[pc + 3];
            if (W0p) {   // layer 0: x @ W0 in fp32 (K=3)
                const float* xp = &inputs[((size_t)b * TDIM + t) * 3];
                float x0 = xp[0], x1 = xp[1], x2 = xp[2];
                zi += x0 * W0p[pc + 0] + x1 * W0p[NG + pc + 0] + x2 * W0p[2 * NG + pc + 0];
                zf += x0 * W0p[pc + 1] + x1 * W0p[NG + pc + 1] + x2 * W0p[2 * NG + pc + 1];
                zg += x0 * W0p[pc + 2] + x1 * W0p[NG + pc + 2] + x2 * W0p[2 * NG + pc + 2];
                zo += x0 * W0p[pc + 3] + x1 * W0p[NG + pc + 3] + x2 * W0p[2 * NG + pc + 3];
            }
            float ig = sigm(zi), fg = sigm(zf), gg = tanhf(zg), og = sigm(zo);
            size_t su = (size_t)b * UDIM + u;
            float cp = cst[su];
            float cc = fg * cp + ig * gg;
            float hc = og * tanhf(cc);
            float tt = times[(size_t)b * TDIM + t];
            float tv = tau[u], sv = sph[u];
            float ph = fmodf(tt - sv, tv);
            ph = (ph < 0.0f ? ph + tv : ph) / tv;   // jnp.mod semantics: in [0,1)
            float kg = (ph < 0.5f * 0.05f) ? (ph * (2.0f / 0.05f))
                     : (ph < 0.05f ? 2.0f - ph * (2.0f / 0.05f) : 0.001f * ph);
            float cn = kg * cc + (1.0f - kg) * cp;
            float hp = hf_prev[su];
            float hn = kg * hc + (1.0f - kg) * hp;
            cst[su] = cn;
            hf_cur[su] = hn;
            hb_cur[su] = __float2bfloat16(hn);
        }
    }
}

// Persistent diagonal-wavefront: one cooperative kernel, grid.sync() per step.
// blocks 0-63 layer0[t=s], 64-127 layer1[t=s-1], 128-135 FC+softmax[t=s-2]
__global__ __launch_bounds__(512, 2)
void persist_kernel(
    const float* __restrict__ inputs, const float* __restrict__ times,
    const float* __restrict__ tau0, const float* __restrict__ s0,
    const float* __restrict__ tau1, const float* __restrict__ s1,
    const float* __restrict__ Wfc, const float* __restrict__ bfc,
    char* __restrict__ ws, float* __restrict__ out)
{
    __shared__ __align__(16) char smem[2 * BUF_BYTES];
    cg::grid_group grid = cg::this_grid();
    const int blk = blockIdx.x;

    __hip_bfloat16* const h0b0 = (__hip_bfloat16*)(ws + OFF_H0B);
    __hip_bfloat16* const h0b1 = (__hip_bfloat16*)(ws + OFF_H0B + SZ_HB);
    __hip_bfloat16* const h1b0 = (__hip_bfloat16*)(ws + OFF_H1B);
    __hip_bfloat16* const h1b1 = (__hip_bfloat16*)(ws + OFF_H1B + SZ_HB);
    float* const h0f0 = (float*)(ws + OFF_H0F);
    float* const h0f1 = (float*)(ws + OFF_H0F + SZ_HF);
    float* const h1f0 = (float*)(ws + OFF_H1F);
    float* const h1f1 = (float*)(ws + OFF_H1F + SZ_HF);
    float* const c0 = (float*)(ws + OFF_C0);
    float* const c1 = (float*)(ws + OFF_C1);
    const __hip_bfloat16* const U0t   = (const __hip_bfloat16*)(ws + OFF_U0T);
    const __hip_bfloat16* const W1U1T = (const __hip_bfloat16*)(ws + OFF_W1U1T);
    const float* const b0p = (const float*)(ws + OFF_B0P);
    const float* const b1p = (const float*)(ws + OFF_B1P);
    const float* const W0p = (const float*)(ws + OFF_W0P);

    for (int s = 0; s < TDIM + 2; ++s) {
        const int pA = (s + 1) & 1;   // parity of step s-1
        const int pB = s & 1;         // parity of step s (== s-2)
        __hip_bfloat16* const h0bA = pA ? h0b1 : h0b0;
        __hip_bfloat16* const h0bB = pB ? h0b1 : h0b0;
        __hip_bfloat16* const h1bA = pA ? h1b1 : h1b0;
        __hip_bfloat16* const h1bB = pB ? h1b1 : h1b0;
        float* const h0fA = pA ? h0f1 : h0f0;
        float* const h0fB = pB ? h0f1 : h0f0;
        float* const h1fA = pA ? h1f1 : h1f0;
        float* const h1fB = pB ? h1f1 : h1f0;

        if (blk < 64) {
            if (s < TDIM)
                cell_tile(smem, blk, s, 512,
                          h0bA, nullptr, U0t, b0p, W0p,
                          inputs, times, tau0, s0,
                          c0, h0fA, h0fB, h0bB);
        } else if (blk < 128) {
            if (s >= 1 && s <= TDIM)
                cell_tile(smem, blk - 64, s - 1, 1024,
                          h0bA, h1bB, W1U1T, b1p, nullptr,
                          inputs, times, tau1, s1,
                          c1, h1fB, h1fA, h1bA);
        } else if (s >= 2) {
            int t = s - 2;
            const float* h = h1fB;
            int wave = threadIdx.x >> 6, lane = threadIdx.x & 63;
            int rbase = (blk - 128) * 64 + wave * 8;
            for (int ri = 0; ri < 8; ++ri) {
                int row = rbase + ri;
                float a[10];
#pragma unroll
                for (int c = 0; c < 10; ++c) a[c] = 0.0f;
                for (int itr = 0; itr < 8; ++itr) {
                    float hv = h[(size_t)row * UDIM + itr * 64 + lane];
                    const float* wp = &Wfc[(size_t)(itr * 64 + lane) * 10];
#pragma unroll
                    for (int c = 0; c < 10; ++c) a[c] += hv * wp[c];
                }
#pragma unroll
                for (int c = 0; c < 10; ++c)
                    for (int m = 32; m; m >>= 1) a[c] += __shfl_xor(a[c], m, 64);
                if (lane == 0) {
                    float mx = -1e30f;
#pragma unroll
                    for (int c = 0; c < 10; ++c) { a[c] += bfc[c]; mx = fmaxf(mx, a[c]); }
                    float sum = 0.0f;
#pragma unroll
                    for (int c = 0; c < 10; ++c) { a[c] = expf(a[c] - mx); sum += a[c]; }
                    float inv = 1.0f / sum;
                    float* op = &out[((size_t)row * TDIM + t) * 10];
#pragma unroll
                    for (int c = 0; c < 10; ++c) op[c] = a[c] * inv;
                }
            }
        }
        grid.sync();
    }
}

extern "C" void kernel_launch(void* const* d_in, const int* in_sizes, int n_in,
                              void* d_out, int out_size, void* d_ws, size_t ws_size,
                              hipStream_t stream) {
    const float* inputs = (const float*)d_in[0];
    const float* times  = (const float*)d_in[1];
    const float* W0   = (const float*)d_in[2];
    const float* U0   = (const float*)d_in[3];
    const float* b0   = (const float*)d_in[4];
    const float* tau0 = (const float*)d_in[5];
    const float* s0   = (const float*)d_in[6];
    const float* W1   = (const float*)d_in[7];
    const float* U1   = (const float*)d_in[8];
    const float* b1   = (const float*)d_in[9];
    const float* tau1 = (const float*)d_in[10];
    const float* s1   = (const float*)d_in[11];
    const float* Wfc  = (const float*)d_in[12];
    const float* bfc  = (const float*)d_in[13];
    float* out = (float*)d_out;
    char* ws = (char*)d_ws;

    hipMemsetAsync(ws + OFF_STATE, 0, STATE_BYTES, stream);
    prep_kernel<<<(NG * 1024) / 256, 256, 0, stream>>>(W0, U0, b0, W1, U1, b1, ws);

    void* kargs[] = {(void*)&inputs, (void*)&times, (void*)&tau0, (void*)&s0,
                     (void*)&tau1, (void*)&s1, (void*)&Wfc, (void*)&bfc,
                     (void*)&ws, (void*)&out};
    hipLaunchCooperativeKernel((const void*)persist_kernel, dim3(136), dim3(512),
                               kargs, 0, stream);
}

// Round 2
// 38506.552 us; speedup vs baseline: 1.0288x; 1.0288x over previous
//
#include <hip/hip_runtime.h>
#include <hip/hip_cooperative_groups.h>
#include <hip/hip_bf16.h>
#include <math.h>

namespace cg = cooperative_groups;

#define TDIM 1024
#define UDIM 512
#define NG   2048   // 4*U

typedef __attribute__((ext_vector_type(8))) short short8;
typedef __attribute__((ext_vector_type(4))) float float4v;

// ---------------- workspace layout ----------------
#define OFF_U0T   ((size_t)0)                       // bf16 [2048][512]  gate-interleaved, transposed
#define SZ_U0T    ((size_t)NG*UDIM*2)
#define OFF_W1U1T (OFF_U0T + SZ_U0T)                // bf16 [2048][1024] (W1 rows 0-511, U1 rows 512-1023)
#define SZ_W1U1T  ((size_t)NG*1024*2)
#define OFF_W0P   (OFF_W1U1T + SZ_W1U1T)            // f32 [3][2048] permuted
#define SZ_W0P    ((size_t)3*NG*4)
#define OFF_B0P   (OFF_W0P + SZ_W0P)
#define OFF_B1P   (OFF_B0P + (size_t)NG*4)
#define OFF_STATE (OFF_B1P + (size_t)NG*4)
#define SZ_HB     ((size_t)512*UDIM*2)              // 512 KB
#define SZ_HF     ((size_t)512*UDIM*4)              // 1 MB
#define OFF_H0B   (OFF_STATE)                       // bf16 x2 ping-pong
#define OFF_H1B   (OFF_H0B + 2*SZ_HB)
#define OFF_H1F   (OFF_H1B + 2*SZ_HB)               // f32 x2 (FC input only)
#define STATE_BYTES (4*SZ_HB + 2*SZ_HF)

__device__ __forceinline__ float sigm(float x) { return 1.0f / (1.0f + expf(-x)); }

__device__ __forceinline__ void gload16(const void* g, void* l) {
    __builtin_amdgcn_global_load_lds(
        (const __attribute__((address_space(1))) void*)g,
        (__attribute__((address_space(3))) void*)l, 16, 0, 0);
}

__device__ __forceinline__ void cell_update(float zi, float zf, float zg, float zo,
                                            float tt, float tv, float sv,
                                            float& cp, float& hp)
{
    float ig = sigm(zi), fg = sigm(zf), gg = tanhf(zg), og = sigm(zo);
    float cc = fg * cp + ig * gg;
    float hc = og * tanhf(cc);
    float ph = fmodf(tt - sv, tv);
    ph = (ph < 0.0f ? ph + tv : ph) / tv;           // jnp.mod semantics: in [0,1)
    float kg = (ph < 0.025f) ? (ph * 40.0f)
             : (ph < 0.05f ? 2.0f - ph * 40.0f : 0.001f * ph);
    cp = kg * cc + (1.0f - kg) * cp;
    hp = kg * hc + (1.0f - kg) * hp;
}

// Weight prep: bf16 convert + transpose to [n',k] + gate-interleave columns
// n' = unit*4 + gate  <-  orig col = gate*512 + unit
__global__ void prep_kernel(const float* __restrict__ W0, const float* __restrict__ U0,
                            const float* __restrict__ b0, const float* __restrict__ W1,
                            const float* __restrict__ U1, const float* __restrict__ b1,
                            char* __restrict__ ws)
{
    int idx = blockIdx.x * 256 + threadIdx.x;   // 2048*1024 total
    int n = idx >> 10;
    int k = idx & 1023;
    int oc = (n & 3) * UDIM + (n >> 2);
    __hip_bfloat16* U0t = (__hip_bfloat16*)(ws + OFF_U0T);
    __hip_bfloat16* Wc  = (__hip_bfloat16*)(ws + OFF_W1U1T);
    float* W0p = (float*)(ws + OFF_W0P);
    float* b0p = (float*)(ws + OFF_B0P);
    float* b1p = (float*)(ws + OFF_B1P);
    if (k < 512) U0t[(size_t)n * 512 + k] = __float2bfloat16(U0[(size_t)k * NG + oc]);
    float wv = (k < 512) ? W1[(size_t)k * NG + oc] : U1[(size_t)(k - 512) * NG + oc];
    Wc[(size_t)n * 1024 + k] = __float2bfloat16(wv);
    if (k < 3) W0p[k * NG + n] = W0[(size_t)k * NG + oc];
    if (k == 0) { b0p[n] = b0[oc]; b1p[n] = b1[oc]; }
}

// ---------------- layer 0: 64 blocks, tile 128 rows x 128 gate-cols, K=512 ----------------
// waves: mg = wave>>2 (row half), nw = wave&3 (32-col slice). Weights in VGPR (full K).
__device__ void layer0_persist(char* smem, int blk,
    const float* __restrict__ inputs, const float* __restrict__ times,
    const float* __restrict__ tau0, const float* __restrict__ s0v, char* __restrict__ ws)
{
    cg::grid_group grid = cg::this_grid();
    const int tid = threadIdx.x;
    const int wave = tid >> 6, lane = tid & 63, lr = lane & 15, lq = lane >> 4;
    const int mg = wave >> 2, nw = wave & 3;
    const int msl = blk >> 4, nsl = blk & 15;
    const int colbase = nsl * 128 + nw * 32;

    const __hip_bfloat16* U0t = (const __hip_bfloat16*)(ws + OFF_U0T);
    const float* b0p = (const float*)(ws + OFF_B0P);
    const float* W0p = (const float*)(ws + OFF_W0P);
    __hip_bfloat16* h0b[2] = {(__hip_bfloat16*)(ws + OFF_H0B),
                              (__hip_bfloat16*)(ws + OFF_H0B + SZ_HB)};

    // persistent B fragments: 2 nf x 16 kk  (128 VGPRs)
    short8 Bf[32];
#pragma unroll
    for (int nf = 0; nf < 2; ++nf)
#pragma unroll
        for (int kk = 0; kk < 16; ++kk)
            Bf[nf * 16 + kk] = *(const short8*)(U0t +
                (size_t)(colbase + nf * 16 + lr) * 512 + kk * 32 + lq * 8);

    // per-thread epilogue cell constants (cells: unit cu, rows crb+16*cc per pass)
    const int cu = tid & 31, crb = tid >> 5;
    const int uu = nsl * 32 + cu;
    const int pcc = nsl * 128 + cu * 4;
    const float4v bias4 = *(const float4v*)(b0p + pcc);
    const float4v w0x = *(const float4v*)(W0p + pcc);
    const float4v w0y = *(const float4v*)(W0p + NG + pcc);
    const float4v w0z = *(const float4v*)(W0p + 2 * NG + pcc);
    const float tv = tau0[uu], sv = s0v[uu];

    float c0r[8], h0r[8];
#pragma unroll
    for (int i = 0; i < 8; ++i) { c0r[i] = 0.0f; h0r[i] = 0.0f; }

    // staging map: tile = 128 rows x 32 k bf16 (8 KB), 64B rows, XOR swizzle
    const int g_row = tid >> 2;
    const int g_q   = (tid & 3) ^ ((g_row >> 1) & 3);

    for (int s = 0; s < TDIM + 2; ++s) {
        if (s < TDIM) {
            const int pA = (s + 1) & 1, pB = s & 1;
            const __hip_bfloat16* Arow = h0b[pA] +
                (size_t)(msl * 128 + g_row) * 512 + g_q * 8;
            // prologue: tiles 0..6 into ring slots 0..6
#pragma unroll
            for (int j = 0; j < 7; ++j)
                gload16(Arow + j * 32, smem + j * 8192 + wave * 1024);

            const float4v z4 = {0.0f, 0.0f, 0.0f, 0.0f};
            float4v acc[4][2];
#pragma unroll
            for (int mf = 0; mf < 4; ++mf) { acc[mf][0] = z4; acc[mf][1] = z4; }

#pragma unroll
            for (int j = 0; j < 16; ++j) {
                asm volatile("s_waitcnt vmcnt(%0)" :: "i"((j + 7 < 16) ? 6 : (15 - j)) : "memory");
                __builtin_amdgcn_s_barrier();
                __builtin_amdgcn_sched_barrier(0);
                if (j + 7 < 16)
                    gload16(Arow + (j + 7) * 32, smem + ((j + 7) & 7) * 8192 + wave * 1024);
                const short* sA = (const short*)(smem + (j & 7) * 8192);
                short8 aF[4];
#pragma unroll
                for (int mf = 0; mf < 4; ++mf) {
                    int row = mg * 64 + mf * 16 + lr;
                    int q = lq ^ ((row >> 1) & 3);
                    aF[mf] = *(const short8*)(sA + row * 32 + q * 8);
                }
#pragma unroll
                for (int mf = 0; mf < 4; ++mf) {
                    acc[mf][0] = __builtin_amdgcn_mfma_f32_16x16x32_bf16(aF[mf], Bf[j],      acc[mf][0], 0, 0, 0);
                    acc[mf][1] = __builtin_amdgcn_mfma_f32_16x16x32_bf16(aF[mf], Bf[16 + j], acc[mf][1], 0, 0, 0);
                }
            }
            __syncthreads();
            float* Z = (float*)smem;   // zone [64][132] f32, two passes (aliases ring)
#pragma unroll
            for (int pass = 0; pass < 2; ++pass) {
                if (mg == pass) {
#pragma unroll
                    for (int mf = 0; mf < 4; ++mf)
#pragma unroll
                        for (int nf = 0; nf < 2; ++nf)
#pragma unroll
                            for (int i = 0; i < 4; ++i)
                                Z[(mf * 16 + lq * 4 + i) * 132 + nw * 32 + nf * 16 + lr] = acc[mf][nf][i];
                }
                __syncthreads();
#pragma unroll
                for (int cc = 0; cc < 4; ++cc) {
                    int rl = crb + 16 * cc;
                    int b = msl * 128 + pass * 64 + rl;
                    float4v z = *(const float4v*)(Z + rl * 132 + cu * 4);
                    const float* xp = inputs + ((size_t)b * TDIM + s) * 3;
                    float x0 = xp[0], x1 = xp[1], x2 = xp[2];
                    float zi = z[0] + bias4[0] + x0 * w0x[0] + x1 * w0y[0] + x2 * w0z[0];
                    float zf = z[1] + bias4[1] + x0 * w0x[1] + x1 * w0y[1] + x2 * w0z[1];
                    float zg = z[2] + bias4[2] + x0 * w0x[2] + x1 * w0y[2] + x2 * w0z[2];
                    float zo = z[3] + bias4[3] + x0 * w0x[3] + x1 * w0y[3] + x2 * w0z[3];
                    float tt = times[(size_t)b * TDIM + s];
                    cell_update(zi, zf, zg, zo, tt, tv, sv, c0r[pass * 4 + cc], h0r[pass * 4 + cc]);
                    h0b[pB][(size_t)b * 512 + uu] = __float2bfloat16(h0r[pass * 4 + cc]);
                }
                __syncthreads();
            }
        }
        grid.sync();
    }
}

// ---------------- layer 1: 128 blocks, tile 64 rows x 128 gate-cols, K=1024 split ----------------
// waves: kg = wave>>2 (K half: h0 / h1), nw = wave&3. Weights in VGPR (half K each).
__device__ void layer1_persist(char* smem, int blk,
    const float* __restrict__ times,
    const float* __restrict__ tau1, const float* __restrict__ s1v, char* __restrict__ ws)
{
    cg::grid_group grid = cg::this_grid();
    const int tid = threadIdx.x;
    const int wave = tid >> 6, lane = tid & 63, lr = lane & 15, lq = lane >> 4;
    const int kg = wave >> 2, nw = wave & 3;
    const int m8 = blk >> 4, nsl = blk & 15;
    const int colbase = nsl * 128 + nw * 32;

    const __hip_bfloat16* Wc = (const __hip_bfloat16*)(ws + OFF_W1U1T);
    const float* b1p = (const float*)(ws + OFF_B1P);
    __hip_bfloat16* h0b[2] = {(__hip_bfloat16*)(ws + OFF_H0B),
                              (__hip_bfloat16*)(ws + OFF_H0B + SZ_HB)};
    __hip_bfloat16* h1b[2] = {(__hip_bfloat16*)(ws + OFF_H1B),
                              (__hip_bfloat16*)(ws + OFF_H1B + SZ_HB)};
    float* h1f[2] = {(float*)(ws + OFF_H1F), (float*)(ws + OFF_H1F + SZ_HF)};

    short8 Bf[32];
#pragma unroll
    for (int nf = 0; nf < 2; ++nf)
#pragma unroll
        for (int kk = 0; kk < 16; ++kk)
            Bf[nf * 16 + kk] = *(const short8*)(Wc +
                (size_t)(colbase + nf * 16 + lr) * 1024 + kg * 512 + kk * 32 + lq * 8);

    const int cu = tid & 31, crb = tid >> 5;
    const int uu = nsl * 32 + cu;
    const int pcc = nsl * 128 + cu * 4;
    const float4v bias4 = *(const float4v*)(b1p + pcc);
    const float tv = tau1[uu], sv = s1v[uu];

    float c1r[4], h1r[4];
#pragma unroll
    for (int i = 0; i < 4; ++i) { c1r[i] = 0.0f; h1r[i] = 0.0f; }

    // staging: tile = 64 rows x 64 k bf16 (8 KB), 128B rows, XOR swizzle; ring[kg][4]
    const int g_row = tid >> 3;
    const int g_q   = (tid & 7) ^ (g_row & 7);

    for (int s = 0; s < TDIM + 2; ++s) {
        if (s >= 1 && s <= TDIM) {
            const int t = s - 1;
            const int pA = (s + 1) & 1, pB = s & 1;
            const __hip_bfloat16* A0 = h0b[pA] + (size_t)(m8 * 64 + g_row) * 512 + g_q * 8;
            const __hip_bfloat16* A1 = h1b[pB] + (size_t)(m8 * 64 + g_row) * 512 + g_q * 8;
#pragma unroll
            for (int J = 0; J < 3; ++J) {
                gload16(A0 + J * 64, smem + (J & 3) * 8192 + wave * 1024);
                gload16(A1 + J * 64, smem + 32768 + (J & 3) * 8192 + wave * 1024);
            }
            const float4v z4 = {0.0f, 0.0f, 0.0f, 0.0f};
            float4v acc[4][2];
#pragma unroll
            for (int mf = 0; mf < 4; ++mf) { acc[mf][0] = z4; acc[mf][1] = z4; }

#pragma unroll
            for (int J = 0; J < 8; ++J) {
                asm volatile("s_waitcnt vmcnt(%0)" :: "i"((J + 2 < 8) ? 4 : ((7 - J) * 2)) : "memory");
                __builtin_amdgcn_s_barrier();
                __builtin_amdgcn_sched_barrier(0);
                if (J + 3 < 8) {
                    gload16(A0 + (J + 3) * 64, smem + ((J + 3) & 3) * 8192 + wave * 1024);
                    gload16(A1 + (J + 3) * 64, smem + 32768 + ((J + 3) & 3) * 8192 + wave * 1024);
                }
                const short* sA = (const short*)(smem + kg * 32768 + (J & 3) * 8192);
#pragma unroll
                for (int kk = 0; kk < 2; ++kk) {
                    short8 aF[4];
#pragma unroll
                    for (int mf = 0; mf < 4; ++mf) {
                        int row = mf * 16 + lr;
                        int q = (kk * 4 + lq) ^ (row & 7);
                        aF[mf] = *(const short8*)(sA + row * 64 + q * 8);
                    }
#pragma unroll
                    for (int mf = 0; mf < 4; ++mf) {
                        acc[mf][0] = __builtin_amdgcn_mfma_f32_16x16x32_bf16(aF[mf], Bf[J * 2 + kk],      acc[mf][0], 0, 0, 0);
                        acc[mf][1] = __builtin_amdgcn_mfma_f32_16x16x32_bf16(aF[mf], Bf[16 + J * 2 + kk], acc[mf][1], 0, 0, 0);
                    }
                }
            }
            __syncthreads();
            float* Z = (float*)smem;   // zone [64][132] f32 (aliases rings)
            if (kg == 1) {
#pragma unroll
                for (int mf = 0; mf < 4; ++mf)
#pragma unroll
                    for (int nf = 0; nf < 2; ++nf)
#pragma unroll
                        for (int i = 0; i < 4; ++i)
                            Z[(mf * 16 + lq * 4 + i) * 132 + nw * 32 + nf * 16 + lr] = acc[mf][nf][i];
            }
            __syncthreads();
            if (kg == 0) {
#pragma unroll
                for (int mf = 0; mf < 4; ++mf)
#pragma unroll
                    for (int nf = 0; nf < 2; ++nf)
#pragma unroll
                        for (int i = 0; i < 4; ++i) {
                            int idx = (mf * 16 + lq * 4 + i) * 132 + nw * 32 + nf * 16 + lr;
                            Z[idx] += acc[mf][nf][i];
                        }
            }
            __syncthreads();
#pragma unroll
            for (int cc = 0; cc < 4; ++cc) {
                int rl = crb + 16 * cc;
                int b = m8 * 64 + rl;
                float4v z = *(const float4v*)(Z + rl * 132 + cu * 4);
                float zi = z[0] + bias4[0];
                float zf = z[1] + bias4[1];
                float zg = z[2] + bias4[2];
                float zo = z[3] + bias4[3];
                float tt = times[(size_t)b * TDIM + t];
                cell_update(zi, zf, zg, zo, tt, tv, sv, c1r[cc], h1r[cc]);
                h1b[pA][(size_t)b * 512 + uu] = __float2bfloat16(h1r[cc]);
                h1f[pA][(size_t)b * 512 + uu] = h1r[cc];
            }
            __syncthreads();
        }
        grid.sync();
    }
}

// ---------------- FC + softmax: 8 blocks x 64 rows ----------------
__device__ void fc_persist(int blk, const float* __restrict__ Wfc, const float* __restrict__ bfc,
                           char* __restrict__ ws, float* __restrict__ out)
{
    cg::grid_group grid = cg::this_grid();
    const int tid = threadIdx.x, wave = tid >> 6, lane = tid & 63;
    const float* h1f[2] = {(const float*)(ws + OFF_H1F), (const float*)(ws + OFF_H1F + SZ_HF)};

    for (int s = 0; s < TDIM + 2; ++s) {
        if (s >= 2) {
            int t = s - 2;
            const float* h = h1f[s & 1];
            int rbase = blk * 64 + wave * 8;
            for (int ri = 0; ri < 8; ++ri) {
                int row = rbase + ri;
                float a[10];
#pragma unroll
                for (int c = 0; c < 10; ++c) a[c] = 0.0f;
                for (int itr = 0; itr < 8; ++itr) {
                    float hv = h[(size_t)row * UDIM + itr * 64 + lane];
                    const float* wp = &Wfc[(size_t)(itr * 64 + lane) * 10];
#pragma unroll
                    for (int c = 0; c < 10; ++c) a[c] += hv * wp[c];
                }
#pragma unroll
                for (int c = 0; c < 10; ++c)
                    for (int m = 32; m; m >>= 1) a[c] += __shfl_xor(a[c], m, 64);
                if (lane == 0) {
                    float mx = -1e30f;
#pragma unroll
                    for (int c = 0; c < 10; ++c) { a[c] += bfc[c]; mx = fmaxf(mx, a[c]); }
                    float sum = 0.0f;
#pragma unroll
                    for (int c = 0; c < 10; ++c) { a[c] = expf(a[c] - mx); sum += a[c]; }
                    float inv = 1.0f / sum;
                    float* op = &out[((size_t)row * TDIM + t) * 10];
#pragma unroll
                    for (int c = 0; c < 10; ++c) op[c] = a[c] * inv;
                }
            }
        }
        grid.sync();
    }
}

// blocks 0-63: layer0   64-191: layer1   192-199: FC
__global__ __launch_bounds__(512, 2)
void persist_kernel(const float* __restrict__ inputs, const float* __restrict__ times,
                    const float* __restrict__ tau0, const float* __restrict__ s0v,
                    const float* __restrict__ tau1, const float* __restrict__ s1v,
                    const float* __restrict__ Wfc, const float* __restrict__ bfc,
                    char* __restrict__ ws, float* __restrict__ out)
{
    __shared__ __align__(16) char smem[65536];
    int blk = blockIdx.x;
    if (blk < 64)       layer0_persist(smem, blk, inputs, times, tau0, s0v, ws);
    else if (blk < 192) layer1_persist(smem, blk - 64, times, tau1, s1v, ws);
    else                fc_persist(blk - 192, Wfc, bfc, ws, out);
}

extern "C" void kernel_launch(void* const* d_in, const int* in_sizes, int n_in,
                              void* d_out, int out_size, void* d_ws, size_t ws_size,
                              hipStream_t stream) {
    const float* inputs = (const float*)d_in[0];
    const float* times  = (const float*)d_in[1];
    const float* W0   = (const float*)d_in[2];
    const float* U0   = (const float*)d_in[3];
    const float* b0   = (const float*)d_in[4];
    const float* tau0 = (const float*)d_in[5];
    const float* s0   = (const float*)d_in[6];
    const float* W1   = (const float*)d_in[7];
    const float* U1   = (const float*)d_in[8];
    const float* b1   = (const float*)d_in[9];
    const float* tau1 = (const float*)d_in[10];
    const float* s1   = (const float*)d_in[11];
    const float* Wfc  = (const float*)d_in[12];
    const float* bfc  = (const float*)d_in[13];
    float* out = (float*)d_out;
    char* ws = (char*)d_ws;

    hipMemsetAsync(ws + OFF_STATE, 0, STATE_BYTES, stream);
    prep_kernel<<<(NG * 1024) / 256, 256, 0, stream>>>(W0, U0, b0, W1, U1, b1, ws);

    void* kargs[] = {(void*)&inputs, (void*)&times, (void*)&tau0, (void*)&s0,
                     (void*)&tau1, (void*)&s1, (void*)&Wfc, (void*)&bfc,
                     (void*)&ws, (void*)&out};
    hipLaunchCooperativeKernel((const void*)persist_kernel, dim3(200), dim3(512),
                               kargs, 0, stream);
}

// Round 3
// 35655.722 us; speedup vs baseline: 1.1110x; 1.0800x over previous
//
#include <hip/hip_runtime.h>
#include <hip/hip_bf16.h>
#include <math.h>

#define TDIM 1024
#define UDIM 512
#define NG   2048   // 4*U
#define NBLK 200

typedef __attribute__((ext_vector_type(8))) short short8;
typedef __attribute__((ext_vector_type(4))) float float4v;

// ---------------- workspace layout ----------------
#define OFF_U0T   ((size_t)0)                       // bf16 [2048][512]  gate-interleaved, transposed
#define SZ_U0T    ((size_t)NG*UDIM*2)
#define OFF_W1U1T (OFF_U0T + SZ_U0T)                // bf16 [2048][1024] (W1 rows 0-511, U1 rows 512-1023)
#define SZ_W1U1T  ((size_t)NG*1024*2)
#define OFF_W0P   (OFF_W1U1T + SZ_W1U1T)            // f32 [3][2048] permuted
#define SZ_W0P    ((size_t)3*NG*4)
#define OFF_B0P   (OFF_W0P + SZ_W0P)
#define OFF_B1P   (OFF_B0P + (size_t)NG*4)
#define OFF_STATE (OFF_B1P + (size_t)NG*4)
#define SZ_HB     ((size_t)512*UDIM*2)              // 512 KB
#define SZ_HF     ((size_t)512*UDIM*4)              // 1 MB
#define OFF_H0B   (OFF_STATE)                       // bf16 x2 ping-pong
#define OFF_H1B   (OFF_H0B + 2*SZ_HB)
#define OFF_H1F   (OFF_H1B + 2*SZ_HB)               // f32 x2 (FC input only)
#define OFF_CNT   (OFF_H1F + 2*SZ_HF)               // barrier counters: 8 sub + 1 root, 128B apart
#define STATE_BYTES (4*SZ_HB + 2*SZ_HF + 4096)

__device__ __forceinline__ float sigm(float x) { return 1.0f / (1.0f + expf(-x)); }

__device__ __forceinline__ void gload16(const void* g, void* l) {
    __builtin_amdgcn_global_load_lds(
        (const __attribute__((address_space(1))) void*)g,
        (__attribute__((address_space(3))) void*)l, 16, 0, 0);
}

// Two-level grid barrier: 8 sub-counters (25 arrivals each) -> 1 root counter.
// Arrival: one ACQ_REL fetch_add (release-flush per block). Spin: RELAXED + s_sleep
// (no per-poll L2 invalidate). Exit: one acquire fence (single L2 inv) per wave.
__device__ __forceinline__ void grid_bar(unsigned* cnts, int s, int blk) {
    __syncthreads();                 // compiler drains vmcnt before s_barrier
    if (threadIdx.x == 0) {
        unsigned* sub  = cnts + (blk & 7) * 32;   // 128B spacing
        unsigned* root = cnts + 8 * 32;
        unsigned old = __hip_atomic_fetch_add(sub, 1u, __ATOMIC_ACQ_REL,
                                              __HIP_MEMORY_SCOPE_AGENT);
        if (old == 25u * (unsigned)(s + 1) - 1u)
            __hip_atomic_fetch_add(root, 1u, __ATOMIC_RELEASE,
                                   __HIP_MEMORY_SCOPE_AGENT);
        unsigned tgt = 8u * (unsigned)(s + 1);
        while (__hip_atomic_load(root, __ATOMIC_RELAXED,
                                 __HIP_MEMORY_SCOPE_AGENT) < tgt)
            __builtin_amdgcn_s_sleep(2);
    }
    __syncthreads();
    __builtin_amdgcn_fence(__ATOMIC_ACQUIRE, "agent");
}

__device__ __forceinline__ void cell_update(float zi, float zf, float zg, float zo,
                                            float tt, float tv, float sv,
                                            float& cp, float& hp)
{
    float ig = sigm(zi), fg = sigm(zf), gg = tanhf(zg), og = sigm(zo);
    float cc = fg * cp + ig * gg;
    float hc = og * tanhf(cc);
    float ph = fmodf(tt - sv, tv);
    ph = (ph < 0.0f ? ph + tv : ph) / tv;           // jnp.mod semantics: in [0,1)
    float kg = (ph < 0.025f) ? (ph * 40.0f)
             : (ph < 0.05f ? 2.0f - ph * 40.0f : 0.001f * ph);
    cp = kg * cc + (1.0f - kg) * cp;
    hp = kg * hc + (1.0f - kg) * hp;
}

// Weight prep: bf16 convert + transpose to [n',k] + gate-interleave columns
// n' = unit*4 + gate  <-  orig col = gate*512 + unit
__global__ void prep_kernel(const float* __restrict__ W0, const float* __restrict__ U0,
                            const float* __restrict__ b0, const float* __restrict__ W1,
                            const float* __restrict__ U1, const float* __restrict__ b1,
                            char* __restrict__ ws)
{
    int idx = blockIdx.x * 256 + threadIdx.x;   // 2048*1024 total
    int n = idx >> 10;
    int k = idx & 1023;
    int oc = (n & 3) * UDIM + (n >> 2);
    __hip_bfloat16* U0t = (__hip_bfloat16*)(ws + OFF_U0T);
    __hip_bfloat16* Wc  = (__hip_bfloat16*)(ws + OFF_W1U1T);
    float* W0p = (float*)(ws + OFF_W0P);
    float* b0p = (float*)(ws + OFF_B0P);
    float* b1p = (float*)(ws + OFF_B1P);
    if (k < 512) U0t[(size_t)n * 512 + k] = __float2bfloat16(U0[(size_t)k * NG + oc]);
    float wv = (k < 512) ? W1[(size_t)k * NG + oc] : U1[(size_t)(k - 512) * NG + oc];
    Wc[(size_t)n * 1024 + k] = __float2bfloat16(wv);
    if (k < 3) W0p[k * NG + n] = W0[(size_t)k * NG + oc];
    if (k == 0) { b0p[n] = b0[oc]; b1p[n] = b1[oc]; }
}

// ---------------- layer 0: 64 blocks, tile 128 rows x 128 gate-cols, K=512 ----------------
__device__ void layer0_persist(char* smem, int blk, int gblk,
    const float* __restrict__ inputs, const float* __restrict__ times,
    const float* __restrict__ tau0, const float* __restrict__ s0v, char* __restrict__ ws)
{
    unsigned* cnts = (unsigned*)(ws + OFF_CNT);
    const int tid = threadIdx.x;
    const int wave = tid >> 6, lane = tid & 63, lr = lane & 15, lq = lane >> 4;
    const int mg = wave >> 2, nw = wave & 3;
    const int msl = blk >> 4, nsl = blk & 15;
    const int colbase = nsl * 128 + nw * 32;

    const __hip_bfloat16* U0t = (const __hip_bfloat16*)(ws + OFF_U0T);
    const float* b0p = (const float*)(ws + OFF_B0P);
    const float* W0p = (const float*)(ws + OFF_W0P);
    __hip_bfloat16* h0b[2] = {(__hip_bfloat16*)(ws + OFF_H0B),
                              (__hip_bfloat16*)(ws + OFF_H0B + SZ_HB)};

    // persistent B fragments: 2 nf x 16 kk  (128 VGPRs)
    short8 Bf[32];
#pragma unroll
    for (int nf = 0; nf < 2; ++nf)
#pragma unroll
        for (int kk = 0; kk < 16; ++kk)
            Bf[nf * 16 + kk] = *(const short8*)(U0t +
                (size_t)(colbase + nf * 16 + lr) * 512 + kk * 32 + lq * 8);

    const int cu = tid & 31, crb = tid >> 5;
    const int uu = nsl * 32 + cu;
    const int pcc = nsl * 128 + cu * 4;
    const float4v bias4 = *(const float4v*)(b0p + pcc);
    const float4v w0x = *(const float4v*)(W0p + pcc);
    const float4v w0y = *(const float4v*)(W0p + NG + pcc);
    const float4v w0z = *(const float4v*)(W0p + 2 * NG + pcc);
    const float tv = tau0[uu], sv = s0v[uu];

    float c0r[8], h0r[8];
#pragma unroll
    for (int i = 0; i < 8; ++i) { c0r[i] = 0.0f; h0r[i] = 0.0f; }

    const int g_row = tid >> 2;
    const int g_q   = (tid & 3) ^ ((g_row >> 1) & 3);

    for (int s = 0; s < TDIM + 2; ++s) {
        if (s < TDIM) {
            const int pA = (s + 1) & 1, pB = s & 1;
            const __hip_bfloat16* Arow = h0b[pA] +
                (size_t)(msl * 128 + g_row) * 512 + g_q * 8;
#pragma unroll
            for (int j = 0; j < 7; ++j)
                gload16(Arow + j * 32, smem + j * 8192 + wave * 1024);

            const float4v z4 = {0.0f, 0.0f, 0.0f, 0.0f};
            float4v acc[4][2];
#pragma unroll
            for (int mf = 0; mf < 4; ++mf) { acc[mf][0] = z4; acc[mf][1] = z4; }

#pragma unroll
            for (int j = 0; j < 16; ++j) {
                asm volatile("s_waitcnt vmcnt(%0)" :: "i"((j + 7 < 16) ? 6 : (15 - j)) : "memory");
                __builtin_amdgcn_s_barrier();
                __builtin_amdgcn_sched_barrier(0);
                if (j + 7 < 16)
                    gload16(Arow + (j + 7) * 32, smem + ((j + 7) & 7) * 8192 + wave * 1024);
                const short* sA = (const short*)(smem + (j & 7) * 8192);
                short8 aF[4];
#pragma unroll
                for (int mf = 0; mf < 4; ++mf) {
                    int row = mg * 64 + mf * 16 + lr;
                    int q = lq ^ ((row >> 1) & 3);
                    aF[mf] = *(const short8*)(sA + row * 32 + q * 8);
                }
#pragma unroll
                for (int mf = 0; mf < 4; ++mf) {
                    acc[mf][0] = __builtin_amdgcn_mfma_f32_16x16x32_bf16(aF[mf], Bf[j],      acc[mf][0], 0, 0, 0);
                    acc[mf][1] = __builtin_amdgcn_mfma_f32_16x16x32_bf16(aF[mf], Bf[16 + j], acc[mf][1], 0, 0, 0);
                }
            }
            __syncthreads();
            float* Z = (float*)smem;   // zone [64][132] f32, two passes (aliases ring)
#pragma unroll
            for (int pass = 0; pass < 2; ++pass) {
                if (mg == pass) {
#pragma unroll
                    for (int mf = 0; mf < 4; ++mf)
#pragma unroll
                        for (int nf = 0; nf < 2; ++nf)
#pragma unroll
                            for (int i = 0; i < 4; ++i)
                                Z[(mf * 16 + lq * 4 + i) * 132 + nw * 32 + nf * 16 + lr] = acc[mf][nf][i];
                }
                __syncthreads();
#pragma unroll
                for (int cc = 0; cc < 4; ++cc) {
                    int rl = crb + 16 * cc;
                    int b = msl * 128 + pass * 64 + rl;
                    float4v z = *(const float4v*)(Z + rl * 132 + cu * 4);
                    const float* xp = inputs + ((size_t)b * TDIM + s) * 3;
                    float x0 = xp[0], x1 = xp[1], x2 = xp[2];
                    float zi = z[0] + bias4[0] + x0 * w0x[0] + x1 * w0y[0] + x2 * w0z[0];
                    float zf = z[1] + bias4[1] + x0 * w0x[1] + x1 * w0y[1] + x2 * w0z[1];
                    float zg = z[2] + bias4[2] + x0 * w0x[2] + x1 * w0y[2] + x2 * w0z[2];
                    float zo = z[3] + bias4[3] + x0 * w0x[3] + x1 * w0y[3] + x2 * w0z[3];
                    float tt = times[(size_t)b * TDIM + s];
                    cell_update(zi, zf, zg, zo, tt, tv, sv, c0r[pass * 4 + cc], h0r[pass * 4 + cc]);
                    h0b[pB][(size_t)b * 512 + uu] = __float2bfloat16(h0r[pass * 4 + cc]);
                }
                __syncthreads();
            }
        }
        grid_bar(cnts, s, gblk);
    }
}

// ---------------- layer 1: 128 blocks, tile 64 rows x 128 gate-cols, K=1024 split ----------------
__device__ void layer1_persist(char* smem, int blk, int gblk,
    const float* __restrict__ times,
    const float* __restrict__ tau1, const float* __restrict__ s1v, char* __restrict__ ws)
{
    unsigned* cnts = (unsigned*)(ws + OFF_CNT);
    const int tid = threadIdx.x;
    const int wave = tid >> 6, lane = tid & 63, lr = lane & 15, lq = lane >> 4;
    const int kg = wave >> 2, nw = wave & 3;
    const int m8 = blk >> 4, nsl = blk & 15;
    const int colbase = nsl * 128 + nw * 32;

    const __hip_bfloat16* Wc = (const __hip_bfloat16*)(ws + OFF_W1U1T);
    const float* b1p = (const float*)(ws + OFF_B1P);
    __hip_bfloat16* h0b[2] = {(__hip_bfloat16*)(ws + OFF_H0B),
                              (__hip_bfloat16*)(ws + OFF_H0B + SZ_HB)};
    __hip_bfloat16* h1b[2] = {(__hip_bfloat16*)(ws + OFF_H1B),
                              (__hip_bfloat16*)(ws + OFF_H1B + SZ_HB)};
    float* h1f[2] = {(float*)(ws + OFF_H1F), (float*)(ws + OFF_H1F + SZ_HF)};

    short8 Bf[32];
#pragma unroll
    for (int nf = 0; nf < 2; ++nf)
#pragma unroll
        for (int kk = 0; kk < 16; ++kk)
            Bf[nf * 16 + kk] = *(const short8*)(Wc +
                (size_t)(colbase + nf * 16 + lr) * 1024 + kg * 512 + kk * 32 + lq * 8);

    const int cu = tid & 31, crb = tid >> 5;
    const int uu = nsl * 32 + cu;
    const int pcc = nsl * 128 + cu * 4;
    const float4v bias4 = *(const float4v*)(b1p + pcc);
    const float tv = tau1[uu], sv = s1v[uu];

    float c1r[4], h1r[4];
#pragma unroll
    for (int i = 0; i < 4; ++i) { c1r[i] = 0.0f; h1r[i] = 0.0f; }

    const int g_row = tid >> 3;
    const int g_q   = (tid & 7) ^ (g_row & 7);

    for (int s = 0; s < TDIM + 2; ++s) {
        if (s >= 1 && s <= TDIM) {
            const int t = s - 1;
            const int pA = (s + 1) & 1, pB = s & 1;
            const __hip_bfloat16* A0 = h0b[pA] + (size_t)(m8 * 64 + g_row) * 512 + g_q * 8;
            const __hip_bfloat16* A1 = h1b[pB] + (size_t)(m8 * 64 + g_row) * 512 + g_q * 8;
#pragma unroll
            for (int J = 0; J < 3; ++J) {
                gload16(A0 + J * 64, smem + (J & 3) * 8192 + wave * 1024);
                gload16(A1 + J * 64, smem + 32768 + (J & 3) * 8192 + wave * 1024);
            }
            const float4v z4 = {0.0f, 0.0f, 0.0f, 0.0f};
            float4v acc[4][2];
#pragma unroll
            for (int mf = 0; mf < 4; ++mf) { acc[mf][0] = z4; acc[mf][1] = z4; }

#pragma unroll
            for (int J = 0; J < 8; ++J) {
                asm volatile("s_waitcnt vmcnt(%0)" :: "i"((J + 2 < 8) ? 4 : ((7 - J) * 2)) : "memory");
                __builtin_amdgcn_s_barrier();
                __builtin_amdgcn_sched_barrier(0);
                if (J + 3 < 8) {
                    gload16(A0 + (J + 3) * 64, smem + ((J + 3) & 3) * 8192 + wave * 1024);
                    gload16(A1 + (J + 3) * 64, smem + 32768 + ((J + 3) & 3) * 8192 + wave * 1024);
                }
                const short* sA = (const short*)(smem + kg * 32768 + (J & 3) * 8192);
#pragma unroll
                for (int kk = 0; kk < 2; ++kk) {
                    short8 aF[4];
#pragma unroll
                    for (int mf = 0; mf < 4; ++mf) {
                        int row = mf * 16 + lr;
                        int q = (kk * 4 + lq) ^ (row & 7);
                        aF[mf] = *(const short8*)(sA + row * 64 + q * 8);
                    }
#pragma unroll
                    for (int mf = 0; mf < 4; ++mf) {
                        acc[mf][0] = __builtin_amdgcn_mfma_f32_16x16x32_bf16(aF[mf], Bf[J * 2 + kk],      acc[mf][0], 0, 0, 0);
                        acc[mf][1] = __builtin_amdgcn_mfma_f32_16x16x32_bf16(aF[mf], Bf[16 + J * 2 + kk], acc[mf][1], 0, 0, 0);
                    }
                }
            }
            __syncthreads();
            float* Z = (float*)smem;   // zone [64][132] f32 (aliases rings)
            if (kg == 1) {
#pragma unroll
                for (int mf = 0; mf < 4; ++mf)
#pragma unroll
                    for (int nf = 0; nf < 2; ++nf)
#pragma unroll
                        for (int i = 0; i < 4; ++i)
                            Z[(mf * 16 + lq * 4 + i) * 132 + nw * 32 + nf * 16 + lr] = acc[mf][nf][i];
            }
            __syncthreads();
            if (kg == 0) {
#pragma unroll
                for (int mf = 0; mf < 4; ++mf)
#pragma unroll
                    for (int nf = 0; nf < 2; ++nf)
#pragma unroll
                        for (int i = 0; i < 4; ++i) {
                            int idx = (mf * 16 + lq * 4 + i) * 132 + nw * 32 + nf * 16 + lr;
                            Z[idx] += acc[mf][nf][i];
                        }
            }
            __syncthreads();
#pragma unroll
            for (int cc = 0; cc < 4; ++cc) {
                int rl = crb + 16 * cc;
                int b = m8 * 64 + rl;
                float4v z = *(const float4v*)(Z + rl * 132 + cu * 4);
                float zi = z[0] + bias4[0];
                float zf = z[1] + bias4[1];
                float zg = z[2] + bias4[2];
                float zo = z[3] + bias4[3];
                float tt = times[(size_t)b * TDIM + t];
                cell_update(zi, zf, zg, zo, tt, tv, sv, c1r[cc], h1r[cc]);
                h1b[pA][(size_t)b * 512 + uu] = __float2bfloat16(h1r[cc]);
                h1f[pA][(size_t)b * 512 + uu] = h1r[cc];
            }
            __syncthreads();
        }
        grid_bar(cnts, s, gblk);
    }
}

// ---------------- FC + softmax: 8 blocks x 64 rows ----------------
__device__ void fc_persist(int blk, int gblk, const float* __restrict__ Wfc,
                           const float* __restrict__ bfc,
                           char* __restrict__ ws, float* __restrict__ out)
{
    unsigned* cnts = (unsigned*)(ws + OFF_CNT);
    const int tid = threadIdx.x, wave = tid >> 6, lane = tid & 63;
    const float* h1f[2] = {(const float*)(ws + OFF_H1F), (const float*)(ws + OFF_H1F + SZ_HF)};

    for (int s = 0; s < TDIM + 2; ++s) {
        if (s >= 2) {
            int t = s - 2;
            const float* h = h1f[s & 1];
            int rbase = blk * 64 + wave * 8;
            for (int ri = 0; ri < 8; ++ri) {
                int row = rbase + ri;
                float a[10];
#pragma unroll
                for (int c = 0; c < 10; ++c) a[c] = 0.0f;
                for (int itr = 0; itr < 8; ++itr) {
                    float hv = h[(size_t)row * UDIM + itr * 64 + lane];
                    const float* wp = &Wfc[(size_t)(itr * 64 + lane) * 10];
#pragma unroll
                    for (int c = 0; c < 10; ++c) a[c] += hv * wp[c];
                }
#pragma unroll
                for (int c = 0; c < 10; ++c)
                    for (int m = 32; m; m >>= 1) a[c] += __shfl_xor(a[c], m, 64);
                if (lane == 0) {
                    float mx = -1e30f;
#pragma unroll
                    for (int c = 0; c < 10; ++c) { a[c] += bfc[c]; mx = fmaxf(mx, a[c]); }
                    float sum = 0.0f;
#pragma unroll
                    for (int c = 0; c < 10; ++c) { a[c] = expf(a[c] - mx); sum += a[c]; }
                    float inv = 1.0f / sum;
                    float* op = &out[((size_t)row * TDIM + t) * 10];
#pragma unroll
                    for (int c = 0; c < 10; ++c) op[c] = a[c] * inv;
                }
            }
        }
        grid_bar(cnts, s, gblk);
    }
}

// blocks 0-63: layer0   64-191: layer1   192-199: FC
__global__ __launch_bounds__(512, 2)
void persist_kernel(const float* __restrict__ inputs, const float* __restrict__ times,
                    const float* __restrict__ tau0, const float* __restrict__ s0v,
                    const float* __restrict__ tau1, const float* __restrict__ s1v,
                    const float* __restrict__ Wfc, const float* __restrict__ bfc,
                    char* __restrict__ ws, float* __restrict__ out)
{
    __shared__ __align__(16) char smem[65536];
    int blk = blockIdx.x;
    if (blk < 64)       layer0_persist(smem, blk, blk, inputs, times, tau0, s0v, ws);
    else if (blk < 192) layer1_persist(smem, blk - 64, blk, times, tau1, s1v, ws);
    else                fc_persist(blk - 192, blk, Wfc, bfc, ws, out);
}

extern "C" void kernel_launch(void* const* d_in, const int* in_sizes, int n_in,
                              void* d_out, int out_size, void* d_ws, size_t ws_size,
                              hipStream_t stream) {
    const float* inputs = (const float*)d_in[0];
    const float* times  = (const float*)d_in[1];
    const float* W0   = (const float*)d_in[2];
    const float* U0   = (const float*)d_in[3];
    const float* b0   = (const float*)d_in[4];
    const float* tau0 = (const float*)d_in[5];
    const float* s0   = (const float*)d_in[6];
    const float* W1   = (const float*)d_in[7];
    const float* U1   = (const float*)d_in[8];
    const float* b1   = (const float*)d_in[9];
    const float* tau1 = (const float*)d_in[10];
    const float* s1   = (const float*)d_in[11];
    const float* Wfc  = (const float*)d_in[12];
    const float* bfc  = (const float*)d_in[13];
    float* out = (float*)d_out;
    char* ws = (char*)d_ws;

    hipMemsetAsync(ws + OFF_STATE, 0, STATE_BYTES, stream);
    prep_kernel<<<(NG * 1024) / 256, 256, 0, stream>>>(W0, U0, b0, W1, U1, b1, ws);

    void* kargs[] = {(void*)&inputs, (void*)&times, (void*)&tau0, (void*)&s0,
                     (void*)&tau1, (void*)&s1, (void*)&Wfc, (void*)&bfc,
                     (void*)&ws, (void*)&out};
    hipLaunchCooperativeKernel((const void*)persist_kernel, dim3(NBLK), dim3(512),
                               kargs, 0, stream);
}

// Round 4
// 28969.525 us; speedup vs baseline: 1.3674x; 1.2308x over previous
//
#include <hip/hip_runtime.h>
#include <hip/hip_bf16.h>
#include <math.h>

#define TDIM 1024
#define UDIM 512
#define NG   2048   // 4*U
#define NBLK 208
#define GARR 52     // arrivals per group: 16 L0 + 32 L1 + 4 FC

typedef __attribute__((ext_vector_type(8))) short short8;
typedef __attribute__((ext_vector_type(4))) float float4v;

// ---------------- workspace layout ----------------
#define OFF_U0T   ((size_t)0)                       // bf16 [2048][512]  gate-interleaved, transposed
#define SZ_U0T    ((size_t)NG*UDIM*2)
#define OFF_W1U1T (OFF_U0T + SZ_U0T)                // bf16 [2048][1024] (W1 rows 0-511, U1 rows 512-1023)
#define SZ_W1U1T  ((size_t)NG*1024*2)
#define OFF_W0P   (OFF_W1U1T + SZ_W1U1T)            // f32 [3][2048] permuted
#define SZ_W0P    ((size_t)3*NG*4)
#define OFF_B0P   (OFF_W0P + SZ_W0P)
#define OFF_B1P   (OFF_B0P + (size_t)NG*4)
#define OFF_STATE (OFF_B1P + (size_t)NG*4)
#define SZ_HB     ((size_t)512*UDIM*2)              // 512 KB
#define SZ_HF     ((size_t)512*UDIM*4)              // 1 MB
#define OFF_H0B   (OFF_STATE)                       // bf16 x2 ping-pong
#define OFF_H1B   (OFF_H0B + 2*SZ_HB)
#define OFF_H1F   (OFF_H1B + 2*SZ_HB)               // f32 x2 (FC input only)
#define OFF_CNT   (OFF_H1F + 2*SZ_HF)               // per-group barrier counters, 2KB apart
#define STATE_BYTES (4*SZ_HB + 2*SZ_HF + 8192)

__device__ __forceinline__ float sigm(float x) { return 1.0f / (1.0f + expf(-x)); }

__device__ __forceinline__ void gload16(const void* g, void* l) {
    __builtin_amdgcn_global_load_lds(
        (const __attribute__((address_space(1))) void*)g,
        (__attribute__((address_space(3))) void*)l, 16, 0, 0);
}

// Per-group barrier: groups are data-closed (batch row-groups of 128), so only
// 52 blocks rendezvous. One counter line per group (2KB apart). Arrival: one
// ACQ_REL fetch_add (release-flush). Spin: RELAXED + s_sleep (no per-poll L2
// invalidate). Exit: one acquire fence.
__device__ __forceinline__ void group_bar(unsigned* cnt, int s) {
    __syncthreads();
    if (threadIdx.x == 0) {
        __hip_atomic_fetch_add(cnt, 1u, __ATOMIC_ACQ_REL, __HIP_MEMORY_SCOPE_AGENT);
        unsigned tgt = (unsigned)GARR * (unsigned)(s + 1);
        while (__hip_atomic_load(cnt, __ATOMIC_RELAXED, __HIP_MEMORY_SCOPE_AGENT) < tgt)
            __builtin_amdgcn_s_sleep(2);
    }
    __syncthreads();
    __builtin_amdgcn_fence(__ATOMIC_ACQUIRE, "agent");
}

__device__ __forceinline__ void cell_update(float zi, float zf, float zg, float zo,
                                            float tt, float tv, float sv,
                                            float& cp, float& hp)
{
    float ig = sigm(zi), fg = sigm(zf), gg = tanhf(zg), og = sigm(zo);
    float cc = fg * cp + ig * gg;
    float hc = og * tanhf(cc);
    float ph = fmodf(tt - sv, tv);
    ph = (ph < 0.0f ? ph + tv : ph) / tv;           // jnp.mod semantics: in [0,1)
    float kg = (ph < 0.025f) ? (ph * 40.0f)
             : (ph < 0.05f ? 2.0f - ph * 40.0f : 0.001f * ph);
    cp = kg * cc + (1.0f - kg) * cp;
    hp = kg * hc + (1.0f - kg) * hp;
}

// Weight prep: bf16 convert + transpose to [n',k] + gate-interleave columns
// n' = unit*4 + gate  <-  orig col = gate*512 + unit
__global__ void prep_kernel(const float* __restrict__ W0, const float* __restrict__ U0,
                            const float* __restrict__ b0, const float* __restrict__ W1,
                            const float* __restrict__ U1, const float* __restrict__ b1,
                            char* __restrict__ ws)
{
    int idx = blockIdx.x * 256 + threadIdx.x;   // 2048*1024 total
    int n = idx >> 10;
    int k = idx & 1023;
    int oc = (n & 3) * UDIM + (n >> 2);
    __hip_bfloat16* U0t = (__hip_bfloat16*)(ws + OFF_U0T);
    __hip_bfloat16* Wc  = (__hip_bfloat16*)(ws + OFF_W1U1T);
    float* W0p = (float*)(ws + OFF_W0P);
    float* b0p = (float*)(ws + OFF_B0P);
    float* b1p = (float*)(ws + OFF_B1P);
    if (k < 512) U0t[(size_t)n * 512 + k] = __float2bfloat16(U0[(size_t)k * NG + oc]);
    float wv = (k < 512) ? W1[(size_t)k * NG + oc] : U1[(size_t)(k - 512) * NG + oc];
    Wc[(size_t)n * 1024 + k] = __float2bfloat16(wv);
    if (k < 3) W0p[k * NG + n] = W0[(size_t)k * NG + oc];
    if (k == 0) { b0p[n] = b0[oc]; b1p[n] = b1[oc]; }
}

// ---------------- layer 0: 64 blocks, tile 128 rows x 128 gate-cols, K=512 ----------------
__device__ void layer0_persist(char* smem, int blk,
    const float* __restrict__ inputs, const float* __restrict__ times,
    const float* __restrict__ tau0, const float* __restrict__ s0v, char* __restrict__ ws)
{
    const int msl = blk >> 4, nsl = blk & 15;
    unsigned* cnt = (unsigned*)(ws + OFF_CNT) + msl * 512;   // group = msl
    const int tid = threadIdx.x;
    const int wave = tid >> 6, lane = tid & 63, lr = lane & 15, lq = lane >> 4;
    const int mg = wave >> 2, nw = wave & 3;
    const int colbase = nsl * 128 + nw * 32;

    const __hip_bfloat16* U0t = (const __hip_bfloat16*)(ws + OFF_U0T);
    const float* b0p = (const float*)(ws + OFF_B0P);
    const float* W0p = (const float*)(ws + OFF_W0P);
    __hip_bfloat16* h0b[2] = {(__hip_bfloat16*)(ws + OFF_H0B),
                              (__hip_bfloat16*)(ws + OFF_H0B + SZ_HB)};

    // persistent B fragments: 2 nf x 16 kk  (128 VGPRs)
    short8 Bf[32];
#pragma unroll
    for (int nf = 0; nf < 2; ++nf)
#pragma unroll
        for (int kk = 0; kk < 16; ++kk)
            Bf[nf * 16 + kk] = *(const short8*)(U0t +
                (size_t)(colbase + nf * 16 + lr) * 512 + kk * 32 + lq * 8);

    const int cu = tid & 31, crb = tid >> 5;
    const int uu = nsl * 32 + cu;
    const int pcc = nsl * 128 + cu * 4;
    const float4v bias4 = *(const float4v*)(b0p + pcc);
    const float4v w0x = *(const float4v*)(W0p + pcc);
    const float4v w0y = *(const float4v*)(W0p + NG + pcc);
    const float4v w0z = *(const float4v*)(W0p + 2 * NG + pcc);
    const float tv = tau0[uu], sv = s0v[uu];

    float c0r[8], h0r[8];
#pragma unroll
    for (int i = 0; i < 8; ++i) { c0r[i] = 0.0f; h0r[i] = 0.0f; }

    const int g_row = tid >> 2;
    const int g_q   = (tid & 3) ^ ((g_row >> 1) & 3);

    for (int s = 0; s < TDIM + 2; ++s) {
        if (s < TDIM) {
            const int pA = (s + 1) & 1, pB = s & 1;
            const __hip_bfloat16* Arow = h0b[pA] +
                (size_t)(msl * 128 + g_row) * 512 + g_q * 8;
#pragma unroll
            for (int j = 0; j < 7; ++j)
                gload16(Arow + j * 32, smem + j * 8192 + wave * 1024);

            const float4v z4 = {0.0f, 0.0f, 0.0f, 0.0f};
            float4v acc[4][2];
#pragma unroll
            for (int mf = 0; mf < 4; ++mf) { acc[mf][0] = z4; acc[mf][1] = z4; }

#pragma unroll
            for (int j = 0; j < 16; ++j) {
                asm volatile("s_waitcnt vmcnt(%0)" :: "i"((j + 7 < 16) ? 6 : (15 - j)) : "memory");
                __builtin_amdgcn_s_barrier();
                __builtin_amdgcn_sched_barrier(0);
                if (j + 7 < 16)
                    gload16(Arow + (j + 7) * 32, smem + ((j + 7) & 7) * 8192 + wave * 1024);
                const short* sA = (const short*)(smem + (j & 7) * 8192);
                short8 aF[4];
#pragma unroll
                for (int mf = 0; mf < 4; ++mf) {
                    int row = mg * 64 + mf * 16 + lr;
                    int q = lq ^ ((row >> 1) & 3);
                    aF[mf] = *(const short8*)(sA + row * 32 + q * 8);
                }
#pragma unroll
                for (int mf = 0; mf < 4; ++mf) {
                    acc[mf][0] = __builtin_amdgcn_mfma_f32_16x16x32_bf16(aF[mf], Bf[j],      acc[mf][0], 0, 0, 0);
                    acc[mf][1] = __builtin_amdgcn_mfma_f32_16x16x32_bf16(aF[mf], Bf[16 + j], acc[mf][1], 0, 0, 0);
                }
            }
            __syncthreads();
            float* Z = (float*)smem;   // zone [64][132] f32, two passes (aliases ring)
#pragma unroll
            for (int pass = 0; pass < 2; ++pass) {
                if (mg == pass) {
#pragma unroll
                    for (int mf = 0; mf < 4; ++mf)
#pragma unroll
                        for (int nf = 0; nf < 2; ++nf)
#pragma unroll
                            for (int i = 0; i < 4; ++i)
                                Z[(mf * 16 + lq * 4 + i) * 132 + nw * 32 + nf * 16 + lr] = acc[mf][nf][i];
                }
                __syncthreads();
#pragma unroll
                for (int cc = 0; cc < 4; ++cc) {
                    int rl = crb + 16 * cc;
                    int b = msl * 128 + pass * 64 + rl;
                    float4v z = *(const float4v*)(Z + rl * 132 + cu * 4);
                    const float* xp = inputs + ((size_t)b * TDIM + s) * 3;
                    float x0 = xp[0], x1 = xp[1], x2 = xp[2];
                    float zi = z[0] + bias4[0] + x0 * w0x[0] + x1 * w0y[0] + x2 * w0z[0];
                    float zf = z[1] + bias4[1] + x0 * w0x[1] + x1 * w0y[1] + x2 * w0z[1];
                    float zg = z[2] + bias4[2] + x0 * w0x[2] + x1 * w0y[2] + x2 * w0z[2];
                    float zo = z[3] + bias4[3] + x0 * w0x[3] + x1 * w0y[3] + x2 * w0z[3];
                    float tt = times[(size_t)b * TDIM + s];
                    cell_update(zi, zf, zg, zo, tt, tv, sv, c0r[pass * 4 + cc], h0r[pass * 4 + cc]);
                    h0b[pB][(size_t)b * 512 + uu] = __float2bfloat16(h0r[pass * 4 + cc]);
                }
                __syncthreads();
            }
        }
        group_bar(cnt, s);
    }
}

// ---------------- layer 1: 128 blocks, tile 64 rows x 128 gate-cols, K=1024 split ----------------
__device__ void layer1_persist(char* smem, int blk,
    const float* __restrict__ times,
    const float* __restrict__ tau1, const float* __restrict__ s1v, char* __restrict__ ws)
{
    const int m8 = blk >> 4, nsl = blk & 15;
    unsigned* cnt = (unsigned*)(ws + OFF_CNT) + (m8 >> 1) * 512;  // group = m8>>1
    const int tid = threadIdx.x;
    const int wave = tid >> 6, lane = tid & 63, lr = lane & 15, lq = lane >> 4;
    const int kg = wave >> 2, nw = wave & 3;
    const int colbase = nsl * 128 + nw * 32;

    const __hip_bfloat16* Wc = (const __hip_bfloat16*)(ws + OFF_W1U1T);
    const float* b1p = (const float*)(ws + OFF_B1P);
    __hip_bfloat16* h0b[2] = {(__hip_bfloat16*)(ws + OFF_H0B),
                              (__hip_bfloat16*)(ws + OFF_H0B + SZ_HB)};
    __hip_bfloat16* h1b[2] = {(__hip_bfloat16*)(ws + OFF_H1B),
                              (__hip_bfloat16*)(ws + OFF_H1B + SZ_HB)};
    float* h1f[2] = {(float*)(ws + OFF_H1F), (float*)(ws + OFF_H1F + SZ_HF)};

    short8 Bf[32];
#pragma unroll
    for (int nf = 0; nf < 2; ++nf)
#pragma unroll
        for (int kk = 0; kk < 16; ++kk)
            Bf[nf * 16 + kk] = *(const short8*)(Wc +
                (size_t)(colbase + nf * 16 + lr) * 1024 + kg * 512 + kk * 32 + lq * 8);

    const int cu = tid & 31, crb = tid >> 5;
    const int uu = nsl * 32 + cu;
    const int pcc = nsl * 128 + cu * 4;
    const float4v bias4 = *(const float4v*)(b1p + pcc);
    const float tv = tau1[uu], sv = s1v[uu];

    float c1r[4], h1r[4];
#pragma unroll
    for (int i = 0; i < 4; ++i) { c1r[i] = 0.0f; h1r[i] = 0.0f; }

    const int g_row = tid >> 3;
    const int g_q   = (tid & 7) ^ (g_row & 7);

    for (int s = 0; s < TDIM + 2; ++s) {
        if (s >= 1 && s <= TDIM) {
            const int t = s - 1;
            const int pA = (s + 1) & 1, pB = s & 1;
            const __hip_bfloat16* A0 = h0b[pA] + (size_t)(m8 * 64 + g_row) * 512 + g_q * 8;
            const __hip_bfloat16* A1 = h1b[pB] + (size_t)(m8 * 64 + g_row) * 512 + g_q * 8;
#pragma unroll
            for (int J = 0; J < 3; ++J) {
                gload16(A0 + J * 64, smem + (J & 3) * 8192 + wave * 1024);
                gload16(A1 + J * 64, smem + 32768 + (J & 3) * 8192 + wave * 1024);
            }
            const float4v z4 = {0.0f, 0.0f, 0.0f, 0.0f};
            float4v acc[4][2];
#pragma unroll
            for (int mf = 0; mf < 4; ++mf) { acc[mf][0] = z4; acc[mf][1] = z4; }

#pragma unroll
            for (int J = 0; J < 8; ++J) {
                asm volatile("s_waitcnt vmcnt(%0)" :: "i"((J + 2 < 8) ? 4 : ((7 - J) * 2)) : "memory");
                __builtin_amdgcn_s_barrier();
                __builtin_amdgcn_sched_barrier(0);
                if (J + 3 < 8) {
                    gload16(A0 + (J + 3) * 64, smem + ((J + 3) & 3) * 8192 + wave * 1024);
                    gload16(A1 + (J + 3) * 64, smem + 32768 + ((J + 3) & 3) * 8192 + wave * 1024);
                }
                const short* sA = (const short*)(smem + kg * 32768 + (J & 3) * 8192);
#pragma unroll
                for (int kk = 0; kk < 2; ++kk) {
                    short8 aF[4];
#pragma unroll
                    for (int mf = 0; mf < 4; ++mf) {
                        int row = mf * 16 + lr;
                        int q = (kk * 4 + lq) ^ (row & 7);
                        aF[mf] = *(const short8*)(sA + row * 64 + q * 8);
                    }
#pragma unroll
                    for (int mf = 0; mf < 4; ++mf) {
                        acc[mf][0] = __builtin_amdgcn_mfma_f32_16x16x32_bf16(aF[mf], Bf[J * 2 + kk],      acc[mf][0], 0, 0, 0);
                        acc[mf][1] = __builtin_amdgcn_mfma_f32_16x16x32_bf16(aF[mf], Bf[16 + J * 2 + kk], acc[mf][1], 0, 0, 0);
                    }
                }
            }
            __syncthreads();
            float* Z = (float*)smem;   // zone [64][132] f32 (aliases rings)
            if (kg == 1) {
#pragma unroll
                for (int mf = 0; mf < 4; ++mf)
#pragma unroll
                    for (int nf = 0; nf < 2; ++nf)
#pragma unroll
                        for (int i = 0; i < 4; ++i)
                            Z[(mf * 16 + lq * 4 + i) * 132 + nw * 32 + nf * 16 + lr] = acc[mf][nf][i];
            }
            __syncthreads();
            if (kg == 0) {
#pragma unroll
                for (int mf = 0; mf < 4; ++mf)
#pragma unroll
                    for (int nf = 0; nf < 2; ++nf)
#pragma unroll
                        for (int i = 0; i < 4; ++i) {
                            int idx = (mf * 16 + lq * 4 + i) * 132 + nw * 32 + nf * 16 + lr;
                            Z[idx] += acc[mf][nf][i];
                        }
            }
            __syncthreads();
#pragma unroll
            for (int cc = 0; cc < 4; ++cc) {
                int rl = crb + 16 * cc;
                int b = m8 * 64 + rl;
                float4v z = *(const float4v*)(Z + rl * 132 + cu * 4);
                float zi = z[0] + bias4[0];
                float zf = z[1] + bias4[1];
                float zg = z[2] + bias4[2];
                float zo = z[3] + bias4[3];
                float tt = times[(size_t)b * TDIM + t];
                cell_update(zi, zf, zg, zo, tt, tv, sv, c1r[cc], h1r[cc]);
                h1b[pA][(size_t)b * 512 + uu] = __float2bfloat16(h1r[cc]);
                h1f[pA][(size_t)b * 512 + uu] = h1r[cc];
            }
            __syncthreads();
        }
        group_bar(cnt, s);
    }
}

// ---------------- FC + softmax: 16 blocks x 32 rows ----------------
__device__ void fc_persist(int blk, const float* __restrict__ Wfc,
                           const float* __restrict__ bfc,
                           char* __restrict__ ws, float* __restrict__ out)
{
    unsigned* cnt = (unsigned*)(ws + OFF_CNT) + (blk >> 2) * 512;  // group = blk>>2
    const int tid = threadIdx.x, wave = tid >> 6, lane = tid & 63;
    const float* h1f[2] = {(const float*)(ws + OFF_H1F), (const float*)(ws + OFF_H1F + SZ_HF)};

    for (int s = 0; s < TDIM + 2; ++s) {
        if (s >= 2) {
            int t = s - 2;
            const float* h = h1f[s & 1];
            int rbase = blk * 32 + wave * 4;
            for (int ri = 0; ri < 4; ++ri) {
                int row = rbase + ri;
                float a[10];
#pragma unroll
                for (int c = 0; c < 10; ++c) a[c] = 0.0f;
                for (int itr = 0; itr < 8; ++itr) {
                    float hv = h[(size_t)row * UDIM + itr * 64 + lane];
                    const float* wp = &Wfc[(size_t)(itr * 64 + lane) * 10];
#pragma unroll
                    for (int c = 0; c < 10; ++c) a[c] += hv * wp[c];
                }
#pragma unroll
                for (int c = 0; c < 10; ++c)
                    for (int m = 32; m; m >>= 1) a[c] += __shfl_xor(a[c], m, 64);
                if (lane == 0) {
                    float mx = -1e30f;
#pragma unroll
                    for (int c = 0; c < 10; ++c) { a[c] += bfc[c]; mx = fmaxf(mx, a[c]); }
                    float sum = 0.0f;
#pragma unroll
                    for (int c = 0; c < 10; ++c) { a[c] = expf(a[c] - mx); sum += a[c]; }
                    float inv = 1.0f / sum;
                    float* op = &out[((size_t)row * TDIM + t) * 10];
#pragma unroll
                    for (int c = 0; c < 10; ++c) op[c] = a[c] * inv;
                }
            }
        }
        group_bar(cnt, s);
    }
}

// blocks 0-63: layer0   64-191: layer1   192-207: FC
// Groups (batch row-groups of 128) are data-closed: group g = L0{msl=g} +
// L1{m8=2g,2g+1} + FC{blk>>2=g}. 52 blocks per group, 4 independent groups.
__global__ __launch_bounds__(512, 2)
void persist_kernel(const float* __restrict__ inputs, const float* __restrict__ times,
                    const float* __restrict__ tau0, const float* __restrict__ s0v,
                    const float* __restrict__ tau1, const float* __restrict__ s1v,
                    const float* __restrict__ Wfc, const float* __restrict__ bfc,
                    char* __restrict__ ws, float* __restrict__ out)
{
    __shared__ __align__(16) char smem[65536];
    int blk = blockIdx.x;
    if (blk < 64)       layer0_persist(smem, blk, inputs, times, tau0, s0v, ws);
    else if (blk < 192) layer1_persist(smem, blk - 64, times, tau1, s1v, ws);
    else                fc_persist(blk - 192, Wfc, bfc, ws, out);
}

extern "C" void kernel_launch(void* const* d_in, const int* in_sizes, int n_in,
                              void* d_out, int out_size, void* d_ws, size_t ws_size,
                              hipStream_t stream) {
    const float* inputs = (const float*)d_in[0];
    const float* times  = (const float*)d_in[1];
    const float* W0   = (const float*)d_in[2];
    const float* U0   = (const float*)d_in[3];
    const float* b0   = (const float*)d_in[4];
    const float* tau0 = (const float*)d_in[5];
    const float* s0   = (const float*)d_in[6];
    const float* W1   = (const float*)d_in[7];
    const float* U1   = (const float*)d_in[8];
    const float* b1   = (const float*)d_in[9];
    const float* tau1 = (const float*)d_in[10];
    const float* s1   = (const float*)d_in[11];
    const float* Wfc  = (const float*)d_in[12];
    const float* bfc  = (const float*)d_in[13];
    float* out = (float*)d_out;
    char* ws = (char*)d_ws;

    hipMemsetAsync(ws + OFF_STATE, 0, STATE_BYTES, stream);
    prep_kernel<<<(NG * 1024) / 256, 256, 0, stream>>>(W0, U0, b0, W1, U1, b1, ws);

    void* kargs[] = {(void*)&inputs, (void*)&times, (void*)&tau0, (void*)&s0,
                     (void*)&tau1, (void*)&s1, (void*)&Wfc, (void*)&bfc,
                     (void*)&ws, (void*)&out};
    hipLaunchCooperativeKernel((const void*)persist_kernel, dim3(NBLK), dim3(512),
                               kargs, 0, stream);
}

// Round 5
// 26369.843 us; speedup vs baseline: 1.5023x; 1.0986x over previous
//
#include <hip/hip_runtime.h>
#include <hip/hip_bf16.h>
#include <math.h>

#define TDIM 1024
#define UDIM 512
#define NG   2048   // 4*U
#define NBLK 208

typedef __attribute__((ext_vector_type(8))) short short8;
typedef __attribute__((ext_vector_type(4))) float float4v;

// ---------------- workspace layout ----------------
#define OFF_U0T   ((size_t)0)                       // bf16 [2048][512]  gate-interleaved, transposed
#define SZ_U0T    ((size_t)NG*UDIM*2)
#define OFF_W1U1T (OFF_U0T + SZ_U0T)                // bf16 [2048][1024] (W1 rows 0-511, U1 rows 512-1023)
#define SZ_W1U1T  ((size_t)NG*1024*2)
#define OFF_W0P   (OFF_W1U1T + SZ_W1U1T)            // f32 [3][2048] permuted
#define SZ_W0P    ((size_t)3*NG*4)
#define OFF_B0P   (OFF_W0P + SZ_W0P)
#define OFF_B1P   (OFF_B0P + (size_t)NG*4)
#define OFF_STATE (OFF_B1P + (size_t)NG*4)
#define SZ_HB     ((size_t)512*UDIM*2)              // 512 KB per slot
#define SZ_HF     ((size_t)512*UDIM*4)              // 1 MB per slot
#define OFF_H0B   (OFF_STATE)                       // bf16 ring x4
#define OFF_H1B   (OFF_H0B + 4*SZ_HB)               // bf16 ring x4
#define OFF_H1F   (OFF_H1B + 4*SZ_HB)               // f32 ring x4 (FC input)
#define OFF_CNT   (OFF_H1F + 4*SZ_HF)               // progress counters
#define STATE_BYTES (8*SZ_HB + 4*SZ_HF + 4096)

#define HSLOT ((size_t)512*UDIM)                    // elements per bf16 slot
#define FSLOT ((size_t)512*UDIM)                    // floats per f32 slot

__device__ __forceinline__ float sigm(float x) { return 1.0f / (1.0f + expf(-x)); }

__device__ __forceinline__ void gload16(const void* g, void* l) {
    __builtin_amdgcn_global_load_lds(
        (const __attribute__((address_space(1))) void*)g,
        (__attribute__((address_space(3))) void*)l, 16, 0, 0);
}

// Dataflow progress counters (monotonic). Wait with register-cached last-seen
// value: slack checks (WAR, 3-step lag) usually skip the load entirely.
__device__ __forceinline__ void wait_ge(unsigned* p, int tgt, unsigned& seen) {
    if ((int)seen >= tgt) return;
    unsigned v = __hip_atomic_load(p, __ATOMIC_RELAXED, __HIP_MEMORY_SCOPE_AGENT);
    while ((int)v < tgt) {
        __builtin_amdgcn_s_sleep(1);
        v = __hip_atomic_load(p, __ATOMIC_RELAXED, __HIP_MEMORY_SCOPE_AGENT);
    }
    seen = v;
}

__device__ __forceinline__ void signal(unsigned* p) {
    __hip_atomic_fetch_add(p, 1u, __ATOMIC_RELEASE, __HIP_MEMORY_SCOPE_AGENT);
}

__device__ __forceinline__ void cell_update(float zi, float zf, float zg, float zo,
                                            float tt, float tv, float sv,
                                            float& cp, float& hp)
{
    float ig = sigm(zi), fg = sigm(zf), gg = tanhf(zg), og = sigm(zo);
    float cc = fg * cp + ig * gg;
    float hc = og * tanhf(cc);
    float ph = fmodf(tt - sv, tv);
    ph = (ph < 0.0f ? ph + tv : ph) / tv;           // jnp.mod semantics: in [0,1)
    float kg = (ph < 0.025f) ? (ph * 40.0f)
             : (ph < 0.05f ? 2.0f - ph * 40.0f : 0.001f * ph);
    cp = kg * cc + (1.0f - kg) * cp;
    hp = kg * hc + (1.0f - kg) * hp;
}

// Weight prep: bf16 convert + transpose to [n',k] + gate-interleave columns
// n' = unit*4 + gate  <-  orig col = gate*512 + unit
__global__ void prep_kernel(const float* __restrict__ W0, const float* __restrict__ U0,
                            const float* __restrict__ b0, const float* __restrict__ W1,
                            const float* __restrict__ U1, const float* __restrict__ b1,
                            char* __restrict__ ws)
{
    int idx = blockIdx.x * 256 + threadIdx.x;   // 2048*1024 total
    int n = idx >> 10;
    int k = idx & 1023;
    int oc = (n & 3) * UDIM + (n >> 2);
    __hip_bfloat16* U0t = (__hip_bfloat16*)(ws + OFF_U0T);
    __hip_bfloat16* Wc  = (__hip_bfloat16*)(ws + OFF_W1U1T);
    float* W0p = (float*)(ws + OFF_W0P);
    float* b0p = (float*)(ws + OFF_B0P);
    float* b1p = (float*)(ws + OFF_B1P);
    if (k < 512) U0t[(size_t)n * 512 + k] = __float2bfloat16(U0[(size_t)k * NG + oc]);
    float wv = (k < 512) ? W1[(size_t)k * NG + oc] : U1[(size_t)(k - 512) * NG + oc];
    Wc[(size_t)n * 1024 + k] = __float2bfloat16(wv);
    if (k < 3) W0p[k * NG + n] = W0[(size_t)k * NG + oc];
    if (k == 0) { b0p[n] = b0[oc]; b1p[n] = b1[oc]; }
}

// ---------------- layer 0: 64 blocks, tile 128 rows x 128 gate-cols, K=512 ----------------
// Waits: RAW h0[s-1] (P0 >= 16s); WAR on h0 slot s&3 (destroys h0[s-4], read by
// L1@s-3): P1 >= 32(s-3). Signals P0 after h0[s] written.
__device__ void layer0_persist(char* smem, int blk,
    const float* __restrict__ inputs, const float* __restrict__ times,
    const float* __restrict__ tau0, const float* __restrict__ s0v, char* __restrict__ ws)
{
    const int msl = blk >> 4, nsl = blk & 15;
    unsigned* cnt = (unsigned*)(ws + OFF_CNT);
    unsigned* P0 = cnt + msl * 32;
    unsigned* P1 = cnt + 128 + msl * 32;
    unsigned seen0 = 0, seen1 = 0;
    const int tid = threadIdx.x;
    const int wave = tid >> 6, lane = tid & 63, lr = lane & 15, lq = lane >> 4;
    const int mg = wave >> 2, nw = wave & 3;
    const int colbase = nsl * 128 + nw * 32;

    const __hip_bfloat16* U0t = (const __hip_bfloat16*)(ws + OFF_U0T);
    const float* b0p = (const float*)(ws + OFF_B0P);
    const float* W0p = (const float*)(ws + OFF_W0P);
    __hip_bfloat16* h0b = (__hip_bfloat16*)(ws + OFF_H0B);

    // persistent B fragments: 2 nf x 16 kk  (128 VGPRs)
    short8 Bf[32];
#pragma unroll
    for (int nf = 0; nf < 2; ++nf)
#pragma unroll
        for (int kk = 0; kk < 16; ++kk)
            Bf[nf * 16 + kk] = *(const short8*)(U0t +
                (size_t)(colbase + nf * 16 + lr) * 512 + kk * 32 + lq * 8);

    const int cu = tid & 31, crb = tid >> 5;
    const int uu = nsl * 32 + cu;
    const int pcc = nsl * 128 + cu * 4;
    const float4v bias4 = *(const float4v*)(b0p + pcc);
    const float4v w0x = *(const float4v*)(W0p + pcc);
    const float4v w0y = *(const float4v*)(W0p + NG + pcc);
    const float4v w0z = *(const float4v*)(W0p + 2 * NG + pcc);
    const float tv = tau0[uu], sv = s0v[uu];

    float c0r[8], h0r[8];
#pragma unroll
    for (int i = 0; i < 8; ++i) { c0r[i] = 0.0f; h0r[i] = 0.0f; }

    const int g_row = tid >> 2;
    const int g_q   = (tid & 3) ^ ((g_row >> 1) & 3);

    for (int s = 0; s < TDIM; ++s) {
        if (tid == 0) {
            wait_ge(P0, 16 * s, seen0);
            if (s >= 4) wait_ge(P1, 32 * (s - 3), seen1);
        }
        __syncthreads();
        __builtin_amdgcn_fence(__ATOMIC_ACQUIRE, "agent");

        const __hip_bfloat16* Arow = h0b + ((size_t)((s + 3) & 3)) * HSLOT +
            (size_t)(msl * 128 + g_row) * 512 + g_q * 8;
        __hip_bfloat16* h0w = h0b + ((size_t)(s & 3)) * HSLOT;
#pragma unroll
        for (int j = 0; j < 7; ++j)
            gload16(Arow + j * 32, smem + j * 8192 + wave * 1024);

        const float4v z4 = {0.0f, 0.0f, 0.0f, 0.0f};
        float4v acc[4][2];
#pragma unroll
        for (int mf = 0; mf < 4; ++mf) { acc[mf][0] = z4; acc[mf][1] = z4; }

#pragma unroll
        for (int j = 0; j < 16; ++j) {
            asm volatile("s_waitcnt vmcnt(%0)" :: "i"((j + 7 < 16) ? 6 : (15 - j)) : "memory");
            __builtin_amdgcn_s_barrier();
            __builtin_amdgcn_sched_barrier(0);
            if (j + 7 < 16)
                gload16(Arow + (j + 7) * 32, smem + ((j + 7) & 7) * 8192 + wave * 1024);
            const short* sA = (const short*)(smem + (j & 7) * 8192);
            short8 aF[4];
#pragma unroll
            for (int mf = 0; mf < 4; ++mf) {
                int row = mg * 64 + mf * 16 + lr;
                int q = lq ^ ((row >> 1) & 3);
                aF[mf] = *(const short8*)(sA + row * 32 + q * 8);
            }
#pragma unroll
            for (int mf = 0; mf < 4; ++mf) {
                acc[mf][0] = __builtin_amdgcn_mfma_f32_16x16x32_bf16(aF[mf], Bf[j],      acc[mf][0], 0, 0, 0);
                acc[mf][1] = __builtin_amdgcn_mfma_f32_16x16x32_bf16(aF[mf], Bf[16 + j], acc[mf][1], 0, 0, 0);
            }
        }
        __syncthreads();
        float* Z = (float*)smem;   // zone [64][132] f32, two passes (aliases ring)
#pragma unroll
        for (int pass = 0; pass < 2; ++pass) {
            if (mg == pass) {
#pragma unroll
                for (int mf = 0; mf < 4; ++mf)
#pragma unroll
                    for (int nf = 0; nf < 2; ++nf)
#pragma unroll
                        for (int i = 0; i < 4; ++i)
                            Z[(mf * 16 + lq * 4 + i) * 132 + nw * 32 + nf * 16 + lr] = acc[mf][nf][i];
            }
            __syncthreads();
#pragma unroll
            for (int cc = 0; cc < 4; ++cc) {
                int rl = crb + 16 * cc;
                int b = msl * 128 + pass * 64 + rl;
                float4v z = *(const float4v*)(Z + rl * 132 + cu * 4);
                const float* xp = inputs + ((size_t)b * TDIM + s) * 3;
                float x0 = xp[0], x1 = xp[1], x2 = xp[2];
                float zi = z[0] + bias4[0] + x0 * w0x[0] + x1 * w0y[0] + x2 * w0z[0];
                float zf = z[1] + bias4[1] + x0 * w0x[1] + x1 * w0y[1] + x2 * w0z[1];
                float zg = z[2] + bias4[2] + x0 * w0x[2] + x1 * w0y[2] + x2 * w0z[2];
                float zo = z[3] + bias4[3] + x0 * w0x[3] + x1 * w0y[3] + x2 * w0z[3];
                float tt = times[(size_t)b * TDIM + s];
                cell_update(zi, zf, zg, zo, tt, tv, sv, c0r[pass * 4 + cc], h0r[pass * 4 + cc]);
                h0w[(size_t)b * 512 + uu] = __float2bfloat16(h0r[pass * 4 + cc]);
            }
            __syncthreads();
        }
        if (tid == 0) signal(P0);
    }
}

// ---------------- layer 1: 128 blocks, tile 64 rows x 128 gate-cols, K=1024 split ----------------
// Waits: RAW h0[s-1] (P0 >= 16s), RAW h1[s-2] (P1 >= 32(s-1)); WAR on h1 slot
// (s-1)&3 (destroys h1[s-5], read by FC@s-3): PF >= 4(s-4). Signals P1.
__device__ void layer1_persist(char* smem, int blk,
    const float* __restrict__ times,
    const float* __restrict__ tau1, const float* __restrict__ s1v, char* __restrict__ ws)
{
    const int m8 = blk >> 4, nsl = blk & 15;
    const int grp = m8 >> 1;
    unsigned* cnt = (unsigned*)(ws + OFF_CNT);
    unsigned* P0 = cnt + grp * 32;
    unsigned* P1 = cnt + 128 + grp * 32;
    unsigned* PF = cnt + 256 + grp * 32;
    unsigned seen0 = 0, seen1 = 0, seenF = 0;
    const int tid = threadIdx.x;
    const int wave = tid >> 6, lane = tid & 63, lr = lane & 15, lq = lane >> 4;
    const int kg = wave >> 2, nw = wave & 3;
    const int colbase = nsl * 128 + nw * 32;

    const __hip_bfloat16* Wc = (const __hip_bfloat16*)(ws + OFF_W1U1T);
    const float* b1p = (const float*)(ws + OFF_B1P);
    __hip_bfloat16* h0b = (__hip_bfloat16*)(ws + OFF_H0B);
    __hip_bfloat16* h1b = (__hip_bfloat16*)(ws + OFF_H1B);
    float* h1f = (float*)(ws + OFF_H1F);

    short8 Bf[32];
#pragma unroll
    for (int nf = 0; nf < 2; ++nf)
#pragma unroll
        for (int kk = 0; kk < 16; ++kk)
            Bf[nf * 16 + kk] = *(const short8*)(Wc +
                (size_t)(colbase + nf * 16 + lr) * 1024 + kg * 512 + kk * 32 + lq * 8);

    const int cu = tid & 31, crb = tid >> 5;
    const int uu = nsl * 32 + cu;
    const int pcc = nsl * 128 + cu * 4;
    const float4v bias4 = *(const float4v*)(b1p + pcc);
    const float tv = tau1[uu], sv = s1v[uu];

    float c1r[4], h1r[4];
#pragma unroll
    for (int i = 0; i < 4; ++i) { c1r[i] = 0.0f; h1r[i] = 0.0f; }

    const int g_row = tid >> 3;
    const int g_q   = (tid & 7) ^ (g_row & 7);

    for (int s = 1; s <= TDIM; ++s) {
        const int t = s - 1;
        if (tid == 0) {
            wait_ge(P0, 16 * s, seen0);
            wait_ge(P1, 32 * (s - 1), seen1);
            if (s >= 5) wait_ge(PF, 4 * (s - 4), seenF);
        }
        __syncthreads();
        __builtin_amdgcn_fence(__ATOMIC_ACQUIRE, "agent");

        const __hip_bfloat16* A0 = h0b + ((size_t)((s + 3) & 3)) * HSLOT +
            (size_t)(m8 * 64 + g_row) * 512 + g_q * 8;
        const __hip_bfloat16* A1 = h1b + ((size_t)((s + 2) & 3)) * HSLOT +
            (size_t)(m8 * 64 + g_row) * 512 + g_q * 8;
        __hip_bfloat16* h1w = h1b + ((size_t)((s + 3) & 3)) * HSLOT;
        float* h1fw = h1f + ((size_t)((s + 3) & 3)) * FSLOT;
#pragma unroll
        for (int J = 0; J < 3; ++J) {
            gload16(A0 + J * 64, smem + (J & 3) * 8192 + wave * 1024);
            gload16(A1 + J * 64, smem + 32768 + (J & 3) * 8192 + wave * 1024);
        }
        const float4v z4 = {0.0f, 0.0f, 0.0f, 0.0f};
        float4v acc[4][2];
#pragma unroll
        for (int mf = 0; mf < 4; ++mf) { acc[mf][0] = z4; acc[mf][1] = z4; }

#pragma unroll
        for (int J = 0; J < 8; ++J) {
            asm volatile("s_waitcnt vmcnt(%0)" :: "i"((J + 2 < 8) ? 4 : ((7 - J) * 2)) : "memory");
            __builtin_amdgcn_s_barrier();
            __builtin_amdgcn_sched_barrier(0);
            if (J + 3 < 8) {
                gload16(A0 + (J + 3) * 64, smem + ((J + 3) & 3) * 8192 + wave * 1024);
                gload16(A1 + (J + 3) * 64, smem + 32768 + ((J + 3) & 3) * 8192 + wave * 1024);
            }
            const short* sA = (const short*)(smem + kg * 32768 + (J & 3) * 8192);
#pragma unroll
            for (int kk = 0; kk < 2; ++kk) {
                short8 aF[4];
#pragma unroll
                for (int mf = 0; mf < 4; ++mf) {
                    int row = mf * 16 + lr;
                    int q = (kk * 4 + lq) ^ (row & 7);
                    aF[mf] = *(const short8*)(sA + row * 64 + q * 8);
                }
#pragma unroll
                for (int mf = 0; mf < 4; ++mf) {
                    acc[mf][0] = __builtin_amdgcn_mfma_f32_16x16x32_bf16(aF[mf], Bf[J * 2 + kk],      acc[mf][0], 0, 0, 0);
                    acc[mf][1] = __builtin_amdgcn_mfma_f32_16x16x32_bf16(aF[mf], Bf[16 + J * 2 + kk], acc[mf][1], 0, 0, 0);
                }
            }
        }
        __syncthreads();
        float* Z = (float*)smem;   // zone [64][132] f32 (aliases rings)
        if (kg == 1) {
#pragma unroll
            for (int mf = 0; mf < 4; ++mf)
#pragma unroll
                for (int nf = 0; nf < 2; ++nf)
#pragma unroll
                    for (int i = 0; i < 4; ++i)
                        Z[(mf * 16 + lq * 4 + i) * 132 + nw * 32 + nf * 16 + lr] = acc[mf][nf][i];
        }
        __syncthreads();
        if (kg == 0) {
#pragma unroll
            for (int mf = 0; mf < 4; ++mf)
#pragma unroll
                for (int nf = 0; nf < 2; ++nf)
#pragma unroll
                    for (int i = 0; i < 4; ++i) {
                        int idx = (mf * 16 + lq * 4 + i) * 132 + nw * 32 + nf * 16 + lr;
                        Z[idx] += acc[mf][nf][i];
                    }
        }
        __syncthreads();
#pragma unroll
        for (int cc = 0; cc < 4; ++cc) {
            int rl = crb + 16 * cc;
            int b = m8 * 64 + rl;
            float4v z = *(const float4v*)(Z + rl * 132 + cu * 4);
            float zi = z[0] + bias4[0];
            float zf = z[1] + bias4[1];
            float zg = z[2] + bias4[2];
            float zo = z[3] + bias4[3];
            float tt = times[(size_t)b * TDIM + t];
            cell_update(zi, zf, zg, zo, tt, tv, sv, c1r[cc], h1r[cc]);
            h1w[(size_t)b * 512 + uu] = __float2bfloat16(h1r[cc]);
            h1fw[(size_t)b * 512 + uu] = h1r[cc];
        }
        __syncthreads();
        if (tid == 0) signal(P1);
    }
}

// ---------------- FC + softmax: 16 blocks x 32 rows ----------------
// Waits: RAW h1f[s-2] (P1 >= 32(s-1)). Signals PF (gates L1's h1 ring reuse).
__device__ void fc_persist(int blk, const float* __restrict__ Wfc,
                           const float* __restrict__ bfc,
                           char* __restrict__ ws, float* __restrict__ out)
{
    const int grp = blk >> 2;
    unsigned* cnt = (unsigned*)(ws + OFF_CNT);
    unsigned* P1 = cnt + 128 + grp * 32;
    unsigned* PF = cnt + 256 + grp * 32;
    unsigned seen1 = 0;
    const int tid = threadIdx.x, wave = tid >> 6, lane = tid & 63;
    const float* h1f = (const float*)(ws + OFF_H1F);

    for (int s = 2; s <= TDIM + 1; ++s) {
        int t = s - 2;
        if (tid == 0) wait_ge(P1, 32 * (s - 1), seen1);
        __syncthreads();
        __builtin_amdgcn_fence(__ATOMIC_ACQUIRE, "agent");
        const float* h = h1f + ((size_t)((s + 2) & 3)) * FSLOT;
        int rbase = blk * 32 + wave * 4;
        for (int ri = 0; ri < 4; ++ri) {
            int row = rbase + ri;
            float a[10];
#pragma unroll
            for (int c = 0; c < 10; ++c) a[c] = 0.0f;
            for (int itr = 0; itr < 8; ++itr) {
                float hv = h[(size_t)row * UDIM + itr * 64 + lane];
                const float* wp = &Wfc[(size_t)(itr * 64 + lane) * 10];
#pragma unroll
                for (int c = 0; c < 10; ++c) a[c] += hv * wp[c];
            }
#pragma unroll
            for (int c = 0; c < 10; ++c)
                for (int m = 32; m; m >>= 1) a[c] += __shfl_xor(a[c], m, 64);
            if (lane == 0) {
                float mx = -1e30f;
#pragma unroll
                for (int c = 0; c < 10; ++c) { a[c] += bfc[c]; mx = fmaxf(mx, a[c]); }
                float sum = 0.0f;
#pragma unroll
                for (int c = 0; c < 10; ++c) { a[c] = expf(a[c] - mx); sum += a[c]; }
                float inv = 1.0f / sum;
                float* op = &out[((size_t)row * TDIM + t) * 10];
#pragma unroll
                for (int c = 0; c < 10; ++c) op[c] = a[c] * inv;
            }
        }
        __syncthreads();
        if (tid == 0) signal(PF);
    }
}

// blocks 0-63: layer0   64-191: layer1   192-207: FC
// Dataflow sync: per row-group progress counters P0 (16/step), P1 (32/step),
// PF (4/step); 4-deep h rings give 3 steps of WAR slack -> roles decouple.
__global__ __launch_bounds__(512, 2)
void persist_kernel(const float* __restrict__ inputs, const float* __restrict__ times,
                    const float* __restrict__ tau0, const float* __restrict__ s0v,
                    const float* __restrict__ tau1, const float* __restrict__ s1v,
                    const float* __restrict__ Wfc, const float* __restrict__ bfc,
                    char* __restrict__ ws, float* __restrict__ out)
{
    __shared__ __align__(16) char smem[65536];
    int blk = blockIdx.x;
    if (blk < 64)       layer0_persist(smem, blk, inputs, times, tau0, s0v, ws);
    else if (blk < 192) layer1_persist(smem, blk - 64, times, tau1, s1v, ws);
    else                fc_persist(blk - 192, Wfc, bfc, ws, out);
}

extern "C" void kernel_launch(void* const* d_in, const int* in_sizes, int n_in,
                              void* d_out, int out_size, void* d_ws, size_t ws_size,
                              hipStream_t stream) {
    const float* inputs = (const float*)d_in[0];
    const float* times  = (const float*)d_in[1];
    const float* W0   = (const float*)d_in[2];
    const float* U0   = (const float*)d_in[3];
    const float* b0   = (const float*)d_in[4];
    const float* tau0 = (const float*)d_in[5];
    const float* s0   = (const float*)d_in[6];
    const float* W1   = (const float*)d_in[7];
    const float* U1   = (const float*)d_in[8];
    const float* b1   = (const float*)d_in[9];
    const float* tau1 = (const float*)d_in[10];
    const float* s1   = (const float*)d_in[11];
    const float* Wfc  = (const float*)d_in[12];
    const float* bfc  = (const float*)d_in[13];
    float* out = (float*)d_out;
    char* ws = (char*)d_ws;

    hipMemsetAsync(ws + OFF_STATE, 0, STATE_BYTES, stream);
    prep_kernel<<<(NG * 1024) / 256, 256, 0, stream>>>(W0, U0, b0, W1, U1, b1, ws);

    void* kargs[] = {(void*)&inputs, (void*)&times, (void*)&tau0, (void*)&s0,
                     (void*)&tau1, (void*)&s1, (void*)&Wfc, (void*)&bfc,
                     (void*)&ws, (void*)&out};
    hipLaunchCooperativeKernel((const void*)persist_kernel, dim3(NBLK), dim3(512),
                               kargs, 0, stream);
}

// Round 6
// 14969.083 us; speedup vs baseline: 2.6464x; 1.7616x over previous
//
#include <hip/hip_runtime.h>
#include <hip/hip_bf16.h>
#include <math.h>

#define TDIM 1024
#define UDIM 512
#define NG   2048   // 4*U
#define NBLK 208

typedef __attribute__((ext_vector_type(8))) short short8;
typedef __attribute__((ext_vector_type(4))) float float4v;

// ---------------- workspace layout ----------------
#define OFF_U0T   ((size_t)0)                       // bf16 [2048][512]  gate-interleaved, transposed
#define SZ_U0T    ((size_t)NG*UDIM*2)
#define OFF_W1U1T (OFF_U0T + SZ_U0T)                // bf16 [2048][1024] (W1 rows 0-511, U1 rows 512-1023)
#define SZ_W1U1T  ((size_t)NG*1024*2)
#define OFF_W0P   (OFF_W1U1T + SZ_W1U1T)            // f32 [3][2048] permuted
#define SZ_W0P    ((size_t)3*NG*4)
#define OFF_B0P   (OFF_W0P + SZ_W0P)
#define OFF_B1P   (OFF_B0P + (size_t)NG*4)
#define OFF_STATE (OFF_B1P + (size_t)NG*4)
#define SZ_HB     ((size_t)512*UDIM*2)              // 512 KB per slot
#define SZ_HF     ((size_t)512*UDIM*4)              // 1 MB per slot
#define OFF_H0B   (OFF_STATE)                       // bf16 ring x4
#define OFF_H1B   (OFF_H0B + 4*SZ_HB)               // bf16 ring x4
#define OFF_H1F   (OFF_H1B + 4*SZ_HB)               // f32 ring x4 (FC input)
#define OFF_CNT   (OFF_H1F + 4*SZ_HF)               // progress counters
#define STATE_BYTES (8*SZ_HB + 4*SZ_HF + 4096)

#define HSLOT ((size_t)512*UDIM)                    // elements per bf16 slot
#define FSLOT ((size_t)512*UDIM)                    // floats per f32 slot

__device__ __forceinline__ float sigm(float x) { return 1.0f / (1.0f + expf(-x)); }

// SC0|SC1 = 17: bypass L1+L2, read/write at the coherent LLC point.
// No buffer_inv / buffer_wbl2 cache maintenance needed anywhere.
__device__ __forceinline__ void gload16(const void* g, void* l) {
    __builtin_amdgcn_global_load_lds(
        (const __attribute__((address_space(1))) void*)g,
        (__attribute__((address_space(3))) void*)l, 16, 0, 17);
}

__device__ __forceinline__ void store_u16_llc(void* p, unsigned short v) {
    asm volatile("global_store_short %0, %1, off sc0 sc1" :: "v"(p), "v"(v) : "memory");
}
__device__ __forceinline__ void store_f32_llc(void* p, float v) {
    asm volatile("global_store_dword %0, %1, off sc0 sc1" :: "v"(p), "v"(v) : "memory");
}

// Dataflow progress counters (monotonic), LLC-resident. Relaxed polls with a
// register-cached last-seen value (slack checks usually skip the load).
__device__ __forceinline__ void wait_ge(unsigned* p, int tgt, unsigned& seen) {
    if ((int)seen >= tgt) return;
    unsigned v = __hip_atomic_load(p, __ATOMIC_RELAXED, __HIP_MEMORY_SCOPE_AGENT);
    while ((int)v < tgt) {
        __builtin_amdgcn_s_sleep(1);
        v = __hip_atomic_load(p, __ATOMIC_RELAXED, __HIP_MEMORY_SCOPE_AGENT);
    }
    seen = v;
}

// All our data stores are SC1 write-through; vmcnt(0) retire == visible at LLC.
// So the flag only needs relaxed ordering after the drain: no release flush.
__device__ __forceinline__ void signal(unsigned* p) {
    asm volatile("s_waitcnt vmcnt(0)" ::: "memory");
    __hip_atomic_fetch_add(p, 1u, __ATOMIC_RELAXED, __HIP_MEMORY_SCOPE_AGENT);
}

__device__ __forceinline__ void cell_update(float zi, float zf, float zg, float zo,
                                            float tt, float tv, float sv,
                                            float& cp, float& hp)
{
    float ig = sigm(zi), fg = sigm(zf), gg = tanhf(zg), og = sigm(zo);
    float cc = fg * cp + ig * gg;
    float hc = og * tanhf(cc);
    float ph = fmodf(tt - sv, tv);
    ph = (ph < 0.0f ? ph + tv : ph) / tv;           // jnp.mod semantics: in [0,1)
    float kg = (ph < 0.025f) ? (ph * 40.0f)
             : (ph < 0.05f ? 2.0f - ph * 40.0f : 0.001f * ph);
    cp = kg * cc + (1.0f - kg) * cp;
    hp = kg * hc + (1.0f - kg) * hp;
}

// Weight prep: bf16 convert + transpose to [n',k] + gate-interleave columns
// n' = unit*4 + gate  <-  orig col = gate*512 + unit
__global__ void prep_kernel(const float* __restrict__ W0, const float* __restrict__ U0,
                            const float* __restrict__ b0, const float* __restrict__ W1,
                            const float* __restrict__ U1, const float* __restrict__ b1,
                            char* __restrict__ ws)
{
    int idx = blockIdx.x * 256 + threadIdx.x;   // 2048*1024 total
    int n = idx >> 10;
    int k = idx & 1023;
    int oc = (n & 3) * UDIM + (n >> 2);
    __hip_bfloat16* U0t = (__hip_bfloat16*)(ws + OFF_U0T);
    __hip_bfloat16* Wc  = (__hip_bfloat16*)(ws + OFF_W1U1T);
    float* W0p = (float*)(ws + OFF_W0P);
    float* b0p = (float*)(ws + OFF_B0P);
    float* b1p = (float*)(ws + OFF_B1P);
    if (k < 512) U0t[(size_t)n * 512 + k] = __float2bfloat16(U0[(size_t)k * NG + oc]);
    float wv = (k < 512) ? W1[(size_t)k * NG + oc] : U1[(size_t)(k - 512) * NG + oc];
    Wc[(size_t)n * 1024 + k] = __float2bfloat16(wv);
    if (k < 3) W0p[k * NG + n] = W0[(size_t)k * NG + oc];
    if (k == 0) { b0p[n] = b0[oc]; b1p[n] = b1[oc]; }
}

// ---------------- layer 0: 64 blocks, tile 128 rows x 128 gate-cols, K=512 ----------------
// Waits: RAW h0[s-1] (P0 >= 16s); WAR on h0 slot s&3 (destroys h0[s-4], read by
// L1@s-3): P1 >= 32(s-3). Signals P0 after h0[s] written (SC1, vmcnt-drained).
__device__ void layer0_persist(char* smem, int blk,
    const float* __restrict__ inputs, const float* __restrict__ times,
    const float* __restrict__ tau0, const float* __restrict__ s0v, char* __restrict__ ws)
{
    const int msl = blk >> 4, nsl = blk & 15;
    unsigned* cnt = (unsigned*)(ws + OFF_CNT);
    unsigned* P0 = cnt + msl * 32;
    unsigned* P1 = cnt + 128 + msl * 32;
    unsigned seen0 = 0, seen1 = 0;
    const int tid = threadIdx.x;
    const int wave = tid >> 6, lane = tid & 63, lr = lane & 15, lq = lane >> 4;
    const int mg = wave >> 2, nw = wave & 3;
    const int colbase = nsl * 128 + nw * 32;

    const __hip_bfloat16* U0t = (const __hip_bfloat16*)(ws + OFF_U0T);
    const float* b0p = (const float*)(ws + OFF_B0P);
    const float* W0p = (const float*)(ws + OFF_W0P);
    __hip_bfloat16* h0b = (__hip_bfloat16*)(ws + OFF_H0B);

    // persistent B fragments: 2 nf x 16 kk  (128 VGPRs)
    short8 Bf[32];
#pragma unroll
    for (int nf = 0; nf < 2; ++nf)
#pragma unroll
        for (int kk = 0; kk < 16; ++kk)
            Bf[nf * 16 + kk] = *(const short8*)(U0t +
                (size_t)(colbase + nf * 16 + lr) * 512 + kk * 32 + lq * 8);

    const int cu = tid & 31, crb = tid >> 5;
    const int uu = nsl * 32 + cu;
    const int pcc = nsl * 128 + cu * 4;
    const float4v bias4 = *(const float4v*)(b0p + pcc);
    const float4v w0x = *(const float4v*)(W0p + pcc);
    const float4v w0y = *(const float4v*)(W0p + NG + pcc);
    const float4v w0z = *(const float4v*)(W0p + 2 * NG + pcc);
    const float tv = tau0[uu], sv = s0v[uu];

    float c0r[8], h0r[8];
#pragma unroll
    for (int i = 0; i < 8; ++i) { c0r[i] = 0.0f; h0r[i] = 0.0f; }

    const int g_row = tid >> 2;
    const int g_q   = (tid & 3) ^ ((g_row >> 1) & 3);

    for (int s = 0; s < TDIM; ++s) {
        if (tid == 0) {
            wait_ge(P0, 16 * s, seen0);
            if (s >= 4) wait_ge(P1, 32 * (s - 3), seen1);
        }
        __syncthreads();

        const __hip_bfloat16* Arow = h0b + ((size_t)((s + 3) & 3)) * HSLOT +
            (size_t)(msl * 128 + g_row) * 512 + g_q * 8;
        __hip_bfloat16* h0w = h0b + ((size_t)(s & 3)) * HSLOT;
#pragma unroll
        for (int j = 0; j < 7; ++j)
            gload16(Arow + j * 32, smem + j * 8192 + wave * 1024);

        const float4v z4 = {0.0f, 0.0f, 0.0f, 0.0f};
        float4v acc[4][2];
#pragma unroll
        for (int mf = 0; mf < 4; ++mf) { acc[mf][0] = z4; acc[mf][1] = z4; }

#pragma unroll
        for (int j = 0; j < 16; ++j) {
            asm volatile("s_waitcnt vmcnt(%0)" :: "i"((j + 7 < 16) ? 6 : (15 - j)) : "memory");
            __builtin_amdgcn_s_barrier();
            __builtin_amdgcn_sched_barrier(0);
            if (j + 7 < 16)
                gload16(Arow + (j + 7) * 32, smem + ((j + 7) & 7) * 8192 + wave * 1024);
            const short* sA = (const short*)(smem + (j & 7) * 8192);
            short8 aF[4];
#pragma unroll
            for (int mf = 0; mf < 4; ++mf) {
                int row = mg * 64 + mf * 16 + lr;
                int q = lq ^ ((row >> 1) & 3);
                aF[mf] = *(const short8*)(sA + row * 32 + q * 8);
            }
#pragma unroll
            for (int mf = 0; mf < 4; ++mf) {
                acc[mf][0] = __builtin_amdgcn_mfma_f32_16x16x32_bf16(aF[mf], Bf[j],      acc[mf][0], 0, 0, 0);
                acc[mf][1] = __builtin_amdgcn_mfma_f32_16x16x32_bf16(aF[mf], Bf[16 + j], acc[mf][1], 0, 0, 0);
            }
        }
        __syncthreads();
        float* Z = (float*)smem;   // zone [64][132] f32, two passes (aliases ring)
#pragma unroll
        for (int pass = 0; pass < 2; ++pass) {
            if (mg == pass) {
#pragma unroll
                for (int mf = 0; mf < 4; ++mf)
#pragma unroll
                    for (int nf = 0; nf < 2; ++nf)
#pragma unroll
                        for (int i = 0; i < 4; ++i)
                            Z[(mf * 16 + lq * 4 + i) * 132 + nw * 32 + nf * 16 + lr] = acc[mf][nf][i];
            }
            __syncthreads();
#pragma unroll
            for (int cc = 0; cc < 4; ++cc) {
                int rl = crb + 16 * cc;
                int b = msl * 128 + pass * 64 + rl;
                float4v z = *(const float4v*)(Z + rl * 132 + cu * 4);
                const float* xp = inputs + ((size_t)b * TDIM + s) * 3;
                float x0 = xp[0], x1 = xp[1], x2 = xp[2];
                float zi = z[0] + bias4[0] + x0 * w0x[0] + x1 * w0y[0] + x2 * w0z[0];
                float zf = z[1] + bias4[1] + x0 * w0x[1] + x1 * w0y[1] + x2 * w0z[1];
                float zg = z[2] + bias4[2] + x0 * w0x[2] + x1 * w0y[2] + x2 * w0z[2];
                float zo = z[3] + bias4[3] + x0 * w0x[3] + x1 * w0y[3] + x2 * w0z[3];
                float tt = times[(size_t)b * TDIM + s];
                cell_update(zi, zf, zg, zo, tt, tv, sv, c0r[pass * 4 + cc], h0r[pass * 4 + cc]);
                __hip_bfloat16 hb = __float2bfloat16(h0r[pass * 4 + cc]);
                store_u16_llc(h0w + (size_t)b * 512 + uu, *(unsigned short*)&hb);
            }
            __syncthreads();
        }
        if (tid == 0) signal(P0);
    }
}

// ---------------- layer 1: 128 blocks, tile 64 rows x 128 gate-cols, K=1024 split ----------------
// Waits: RAW h0[s-1] (P0 >= 16s), RAW h1[s-2] (P1 >= 32(s-1)); WAR on h1 slot
// (s+3)&3 (destroys h1[s-5], staged by FC@s-3): PF >= 4(s-4). Signals P1.
__device__ void layer1_persist(char* smem, int blk,
    const float* __restrict__ times,
    const float* __restrict__ tau1, const float* __restrict__ s1v, char* __restrict__ ws)
{
    const int m8 = blk >> 4, nsl = blk & 15;
    const int grp = m8 >> 1;
    unsigned* cnt = (unsigned*)(ws + OFF_CNT);
    unsigned* P0 = cnt + grp * 32;
    unsigned* P1 = cnt + 128 + grp * 32;
    unsigned* PF = cnt + 256 + grp * 32;
    unsigned seen0 = 0, seen1 = 0, seenF = 0;
    const int tid = threadIdx.x;
    const int wave = tid >> 6, lane = tid & 63, lr = lane & 15, lq = lane >> 4;
    const int kg = wave >> 2, nw = wave & 3;
    const int colbase = nsl * 128 + nw * 32;

    const __hip_bfloat16* Wc = (const __hip_bfloat16*)(ws + OFF_W1U1T);
    const float* b1p = (const float*)(ws + OFF_B1P);
    __hip_bfloat16* h0b = (__hip_bfloat16*)(ws + OFF_H0B);
    __hip_bfloat16* h1b = (__hip_bfloat16*)(ws + OFF_H1B);
    float* h1f = (float*)(ws + OFF_H1F);

    short8 Bf[32];
#pragma unroll
    for (int nf = 0; nf < 2; ++nf)
#pragma unroll
        for (int kk = 0; kk < 16; ++kk)
            Bf[nf * 16 + kk] = *(const short8*)(Wc +
                (size_t)(colbase + nf * 16 + lr) * 1024 + kg * 512 + kk * 32 + lq * 8);

    const int cu = tid & 31, crb = tid >> 5;
    const int uu = nsl * 32 + cu;
    const int pcc = nsl * 128 + cu * 4;
    const float4v bias4 = *(const float4v*)(b1p + pcc);
    const float tv = tau1[uu], sv = s1v[uu];

    float c1r[4], h1r[4];
#pragma unroll
    for (int i = 0; i < 4; ++i) { c1r[i] = 0.0f; h1r[i] = 0.0f; }

    const int g_row = tid >> 3;
    const int g_q   = (tid & 7) ^ (g_row & 7);

    for (int s = 1; s <= TDIM; ++s) {
        const int t = s - 1;
        if (tid == 0) {
            wait_ge(P0, 16 * s, seen0);
            wait_ge(P1, 32 * (s - 1), seen1);
            if (s >= 5) wait_ge(PF, 4 * (s - 4), seenF);
        }
        __syncthreads();

        const __hip_bfloat16* A0 = h0b + ((size_t)((s + 3) & 3)) * HSLOT +
            (size_t)(m8 * 64 + g_row) * 512 + g_q * 8;
        const __hip_bfloat16* A1 = h1b + ((size_t)((s + 2) & 3)) * HSLOT +
            (size_t)(m8 * 64 + g_row) * 512 + g_q * 8;
        __hip_bfloat16* h1w = h1b + ((size_t)((s + 3) & 3)) * HSLOT;
        float* h1fw = h1f + ((size_t)((s + 3) & 3)) * FSLOT;
#pragma unroll
        for (int J = 0; J < 3; ++J) {
            gload16(A0 + J * 64, smem + (J & 3) * 8192 + wave * 1024);
            gload16(A1 + J * 64, smem + 32768 + (J & 3) * 8192 + wave * 1024);
        }
        const float4v z4 = {0.0f, 0.0f, 0.0f, 0.0f};
        float4v acc[4][2];
#pragma unroll
        for (int mf = 0; mf < 4; ++mf) { acc[mf][0] = z4; acc[mf][1] = z4; }

#pragma unroll
        for (int J = 0; J < 8; ++J) {
            asm volatile("s_waitcnt vmcnt(%0)" :: "i"((J + 2 < 8) ? 4 : ((7 - J) * 2)) : "memory");
            __builtin_amdgcn_s_barrier();
            __builtin_amdgcn_sched_barrier(0);
            if (J + 3 < 8) {
                gload16(A0 + (J + 3) * 64, smem + ((J + 3) & 3) * 8192 + wave * 1024);
                gload16(A1 + (J + 3) * 64, smem + 32768 + ((J + 3) & 3) * 8192 + wave * 1024);
            }
            const short* sA = (const short*)(smem + kg * 32768 + (J & 3) * 8192);
#pragma unroll
            for (int kk = 0; kk < 2; ++kk) {
                short8 aF[4];
#pragma unroll
                for (int mf = 0; mf < 4; ++mf) {
                    int row = mf * 16 + lr;
                    int q = (kk * 4 + lq) ^ (row & 7);
                    aF[mf] = *(const short8*)(sA + row * 64 + q * 8);
                }
#pragma unroll
                for (int mf = 0; mf < 4; ++mf) {
                    acc[mf][0] = __builtin_amdgcn_mfma_f32_16x16x32_bf16(aF[mf], Bf[J * 2 + kk],      acc[mf][0], 0, 0, 0);
                    acc[mf][1] = __builtin_amdgcn_mfma_f32_16x16x32_bf16(aF[mf], Bf[16 + J * 2 + kk], acc[mf][1], 0, 0, 0);
                }
            }
        }
        __syncthreads();
        float* Z = (float*)smem;   // zone [64][132] f32 (aliases rings)
        if (kg == 1) {
#pragma unroll
            for (int mf = 0; mf < 4; ++mf)
#pragma unroll
                for (int nf = 0; nf < 2; ++nf)
#pragma unroll
                    for (int i = 0; i < 4; ++i)
                        Z[(mf * 16 + lq * 4 + i) * 132 + nw * 32 + nf * 16 + lr] = acc[mf][nf][i];
        }
        __syncthreads();
        if (kg == 0) {
#pragma unroll
            for (int mf = 0; mf < 4; ++mf)
#pragma unroll
                for (int nf = 0; nf < 2; ++nf)
#pragma unroll
                    for (int i = 0; i < 4; ++i) {
                        int idx = (mf * 16 + lq * 4 + i) * 132 + nw * 32 + nf * 16 + lr;
                        Z[idx] += acc[mf][nf][i];
                    }
        }
        __syncthreads();
#pragma unroll
        for (int cc = 0; cc < 4; ++cc) {
            int rl = crb + 16 * cc;
            int b = m8 * 64 + rl;
            float4v z = *(const float4v*)(Z + rl * 132 + cu * 4);
            float zi = z[0] + bias4[0];
            float zf = z[1] + bias4[1];
            float zg = z[2] + bias4[2];
            float zo = z[3] + bias4[3];
            float tt = times[(size_t)b * TDIM + t];
            cell_update(zi, zf, zg, zo, tt, tv, sv, c1r[cc], h1r[cc]);
            __hip_bfloat16 hb = __float2bfloat16(h1r[cc]);
            store_u16_llc(h1w + (size_t)b * 512 + uu, *(unsigned short*)&hb);
            store_f32_llc(h1fw + (size_t)b * 512 + uu, h1r[cc]);
        }
        __syncthreads();
        if (tid == 0) signal(P1);
    }
}

// ---------------- FC + softmax: 16 blocks x 32 rows ----------------
// Stages its 32x512 f32 h1f slice into LDS (SC1 global_load_lds), signals PF
// right after staging (early ring release), then computes from LDS.
__device__ void fc_persist(char* smem, int blk, const float* __restrict__ Wfc,
                           const float* __restrict__ bfc,
                           char* __restrict__ ws, float* __restrict__ out)
{
    const int grp = blk >> 2;
    unsigned* cnt = (unsigned*)(ws + OFF_CNT);
    unsigned* P1 = cnt + 128 + grp * 32;
    unsigned* PF = cnt + 256 + grp * 32;
    unsigned seen1 = 0;
    const int tid = threadIdx.x, wave = tid >> 6, lane = tid & 63;
    const float* h1f = (const float*)(ws + OFF_H1F);
    const int rbase = blk * 32;

    for (int s = 2; s <= TDIM + 1; ++s) {
        int t = s - 2;
        if (tid == 0) wait_ge(P1, 32 * (s - 1), seen1);
        __syncthreads();
        const char* h = (const char*)(h1f + ((size_t)((s + 2) & 3)) * FSLOT +
                                      (size_t)rbase * 512);
        // stage 32 rows x 512 f32 = 64KB: 8 chunks of 16B per thread
#pragma unroll
        for (int k = 0; k < 8; ++k)
            gload16(h + ((size_t)(tid + k * 512)) * 16, smem + k * 8192 + wave * 1024);
        asm volatile("s_waitcnt vmcnt(0)" ::: "memory");
        __syncthreads();
        if (tid == 0) signal(PF);   // slot consumed into LDS; L1 may reuse it
        const float* hl = (const float*)smem;
        for (int ri = 0; ri < 4; ++ri) {
            int rl = wave * 4 + ri;
            int row = rbase + rl;
            float a[10];
#pragma unroll
            for (int c = 0; c < 10; ++c) a[c] = 0.0f;
#pragma unroll
            for (int itr = 0; itr < 8; ++itr) {
                float hv = hl[(size_t)rl * 512 + itr * 64 + lane];
                const float* wp = &Wfc[(size_t)(itr * 64 + lane) * 10];
#pragma unroll
                for (int c = 0; c < 10; ++c) a[c] += hv * wp[c];
            }
#pragma unroll
            for (int c = 0; c < 10; ++c)
                for (int m = 32; m; m >>= 1) a[c] += __shfl_xor(a[c], m, 64);
            if (lane == 0) {
                float mx = -1e30f;
#pragma unroll
                for (int c = 0; c < 10; ++c) { a[c] += bfc[c]; mx = fmaxf(mx, a[c]); }
                float sum = 0.0f;
#pragma unroll
                for (int c = 0; c < 10; ++c) { a[c] = expf(a[c] - mx); sum += a[c]; }
                float inv = 1.0f / sum;
                float* op = &out[((size_t)row * TDIM + t) * 10];
#pragma unroll
                for (int c = 0; c < 10; ++c) op[c] = a[c] * inv;
            }
        }
        __syncthreads();
    }
}

// blocks 0-63: layer0   64-191: layer1   192-207: FC
// Dataflow sync: per row-group progress counters P0 (16/step), P1 (32/step),
// PF (4/step); 4-deep h rings; all exchanged data SC0|SC1 (LLC-coherent) so
// no cache-maintenance ops (wbl2/inv) are ever issued.
__global__ __launch_bounds__(512, 2)
void persist_kernel(const float* __restrict__ inputs, const float* __restrict__ times,
                    const float* __restrict__ tau0, const float* __restrict__ s0v,
                    const float* __restrict__ tau1, const float* __restrict__ s1v,
                    const float* __restrict__ Wfc, const float* __restrict__ bfc,
                    char* __restrict__ ws, float* __restrict__ out)
{
    __shared__ __align__(16) char smem[65536];
    int blk = blockIdx.x;
    if (blk < 64)       layer0_persist(smem, blk, inputs, times, tau0, s0v, ws);
    else if (blk < 192) layer1_persist(smem, blk - 64, times, tau1, s1v, ws);
    else                fc_persist(smem, blk - 192, Wfc, bfc, ws, out);
}

extern "C" void kernel_launch(void* const* d_in, const int* in_sizes, int n_in,
                              void* d_out, int out_size, void* d_ws, size_t ws_size,
                              hipStream_t stream) {
    const float* inputs = (const float*)d_in[0];
    const float* times  = (const float*)d_in[1];
    const float* W0   = (const float*)d_in[2];
    const float* U0   = (const float*)d_in[3];
    const float* b0   = (const float*)d_in[4];
    const float* tau0 = (const float*)d_in[5];
    const float* s0   = (const float*)d_in[6];
    const float* W1   = (const float*)d_in[7];
    const float* U1   = (const float*)d_in[8];
    const float* b1   = (const float*)d_in[9];
    const float* tau1 = (const float*)d_in[10];
    const float* s1   = (const float*)d_in[11];
    const float* Wfc  = (const float*)d_in[12];
    const float* bfc  = (const float*)d_in[13];
    float* out = (float*)d_out;
    char* ws = (char*)d_ws;

    hipMemsetAsync(ws + OFF_STATE, 0, STATE_BYTES, stream);
    prep_kernel<<<(NG * 1024) / 256, 256, 0, stream>>>(W0, U0, b0, W1, U1, b1, ws);

    void* kargs[] = {(void*)&inputs, (void*)&times, (void*)&tau0, (void*)&s0,
                     (void*)&tau1, (void*)&s1, (void*)&Wfc, (void*)&bfc,
                     (void*)&ws, (void*)&out};
    hipLaunchCooperativeKernel((const void*)persist_kernel, dim3(NBLK), dim3(512),
                               kargs, 0, stream);
}

// Round 7
// 12336.604 us; speedup vs baseline: 3.2111x; 1.2134x over previous
//
#include <hip/hip_runtime.h>
#include <hip/hip_bf16.h>
#include <math.h>

#define TDIM 1024
#define UDIM 512
#define NG   2048   // 4*U
#define NBLK 208

typedef __attribute__((ext_vector_type(8))) short short8;
typedef __attribute__((ext_vector_type(4))) float float4v;

// ---------------- workspace layout ----------------
#define OFF_U0T   ((size_t)0)                       // bf16 [2048][512]  gate-interleaved, transposed
#define SZ_U0T    ((size_t)NG*UDIM*2)
#define OFF_W1U1T (OFF_U0T + SZ_U0T)                // bf16 [2048][1024] (W1 rows 0-511, U1 rows 512-1023)
#define SZ_W1U1T  ((size_t)NG*1024*2)
#define OFF_W0P   (OFF_W1U1T + SZ_W1U1T)            // f32 [3][2048] permuted
#define SZ_W0P    ((size_t)3*NG*4)
#define OFF_B0P   (OFF_W0P + SZ_W0P)
#define OFF_B1P   (OFF_B0P + (size_t)NG*4)
#define OFF_STATE (OFF_B1P + (size_t)NG*4)
#define SZ_HB     ((size_t)512*UDIM*2)              // 512 KB per slot
#define SZ_HF     ((size_t)512*UDIM*4)              // 1 MB per slot
#define OFF_H0B   (OFF_STATE)                       // bf16 ring x4
#define OFF_H1B   (OFF_H0B + 4*SZ_HB)               // bf16 ring x4
#define OFF_H1F   (OFF_H1B + 4*SZ_HB)               // f32 ring x4 (FC input)
#define OFF_CNT   (OFF_H1F + 4*SZ_HF)               // progress counters
#define STATE_BYTES (8*SZ_HB + 4*SZ_HF + 4096)

#define HSLOT ((size_t)512*UDIM)                    // elements per bf16 slot
#define FSLOT ((size_t)512*UDIM)                    // floats per f32 slot

// counter layout (dwords from cnt):
//  P0G:  g*16 + nsl                  [0,64)    L0 per-producer, stores s+1 after step s
//  P1G:  64 + g*32 + half*16 + nsl   [64,192)  L1 per-producer, stores s after step s
//  PF :  192 + g*16                  [192,256) FC aggregated fetch_add

// fast math: hardware exp/rcp based
__device__ __forceinline__ float rcpf(float x) { return __builtin_amdgcn_rcpf(x); }
__device__ __forceinline__ float sigm(float x) { return rcpf(1.0f + __expf(-x)); }
__device__ __forceinline__ float tanhfast(float x) { return 1.0f - 2.0f * rcpf(1.0f + __expf(2.0f * x)); }

// SC0|SC1 = 17: bypass L1+L2, read/write at the coherent LLC point.
__device__ __forceinline__ void gload16(const void* g, void* l) {
    __builtin_amdgcn_global_load_lds(
        (const __attribute__((address_space(1))) void*)g,
        (__attribute__((address_space(3))) void*)l, 16, 0, 17);
}

__device__ __forceinline__ void store_u16_llc(void* p, unsigned short v) {
    asm volatile("global_store_short %0, %1, off sc0 sc1" :: "v"(p), "v"(v) : "memory");
}
__device__ __forceinline__ void store_f32_llc(void* p, float v) {
    asm volatile("global_store_dword %0, %1, off sc0 sc1" :: "v"(p), "v"(v) : "memory");
}
__device__ __forceinline__ void store_cnt(unsigned* p, unsigned v) {
    asm volatile("global_store_dword %0, %1, off sc0 sc1" :: "v"(p), "v"(v) : "memory");
}

// lane-parallel min over 16/32 per-producer counters: one vector load + shfl
// reduce. All waves execute (self-gating, no thread0+syncthreads relay).
__device__ __forceinline__ int minv(const unsigned* base, int lanemask) {
    unsigned u = __hip_atomic_load(base + (threadIdx.x & lanemask),
                                   __ATOMIC_RELAXED, __HIP_MEMORY_SCOPE_AGENT);
    int x = (int)u;
#pragma unroll
    for (int m = 32; m; m >>= 1) x = min(x, __shfl_xor(x, m, 64));
    return x;
}
__device__ __forceinline__ void wait_min(const unsigned* base, int lanemask,
                                         int tgt, int& seen) {
    while (seen < tgt) {
        seen = minv(base, lanemask);
        if (seen < tgt) __builtin_amdgcn_s_sleep(2);
    }
}
__device__ __forceinline__ void wait_val(unsigned* p, int tgt, int& seen) {
    while (seen < tgt) {
        seen = (int)__hip_atomic_load(p, __ATOMIC_RELAXED, __HIP_MEMORY_SCOPE_AGENT);
        if (seen < tgt) __builtin_amdgcn_s_sleep(2);
    }
}

__device__ __forceinline__ void cell_update(float zi, float zf, float zg, float zo,
                                            float tt, float tvi, float sv,
                                            float& cp, float& hp)
{
    float ig = sigm(zi), fg = sigm(zf), gg = tanhfast(zg), og = sigm(zo);
    float cc = fg * cp + ig * gg;
    float hc = og * tanhfast(cc);
    float q  = (tt - sv) * tvi;
    float ph = q - floorf(q);                       // == mod(t-s,tau)/tau in [0,1)
    float kg = (ph < 0.025f) ? (ph * 40.0f)
             : (ph < 0.05f ? 2.0f - ph * 40.0f : 0.001f * ph);
    cp = kg * cc + (1.0f - kg) * cp;
    hp = kg * hc + (1.0f - kg) * hp;
}

// Weight prep: bf16 convert + transpose to [n',k] + gate-interleave columns
// n' = unit*4 + gate  <-  orig col = gate*512 + unit
__global__ void prep_kernel(const float* __restrict__ W0, const float* __restrict__ U0,
                            const float* __restrict__ b0, const float* __restrict__ W1,
                            const float* __restrict__ U1, const float* __restrict__ b1,
                            char* __restrict__ ws)
{
    int idx = blockIdx.x * 256 + threadIdx.x;   // 2048*1024 total
    int n = idx >> 10;
    int k = idx & 1023;
    int oc = (n & 3) * UDIM + (n >> 2);
    __hip_bfloat16* U0t = (__hip_bfloat16*)(ws + OFF_U0T);
    __hip_bfloat16* Wc  = (__hip_bfloat16*)(ws + OFF_W1U1T);
    float* W0p = (float*)(ws + OFF_W0P);
    float* b0p = (float*)(ws + OFF_B0P);
    float* b1p = (float*)(ws + OFF_B1P);
    if (k < 512) U0t[(size_t)n * 512 + k] = __float2bfloat16(U0[(size_t)k * NG + oc]);
    float wv = (k < 512) ? W1[(size_t)k * NG + oc] : U1[(size_t)(k - 512) * NG + oc];
    Wc[(size_t)n * 1024 + k] = __float2bfloat16(wv);
    if (k < 3) W0p[k * NG + n] = W0[(size_t)k * NG + oc];
    if (k == 0) { b0p[n] = b0[oc]; b1p[n] = b1[oc]; }
}

// ---------------- layer 0: 64 blocks, tile 128 rows x 128 gate-cols, K=512 ----------------
// RAW h0[s-1]: min16(P0G[g]) >= s. WAR (h0 slot s&3, read by L1@s-3):
// min32(P1G[g]) >= s-3 (3-step slack, value-cached skip). Signals own P0G dword.
// k-tile order rotated by nsl (LLC spread); 2 tiles per barrier round.
__device__ void layer0_persist(char* smem, int blk,
    const float* __restrict__ inputs, const float* __restrict__ times,
    const float* __restrict__ tau0, const float* __restrict__ s0v, char* __restrict__ ws)
{
    const int msl = blk >> 4, nsl = blk & 15;
    unsigned* cnt = (unsigned*)(ws + OFF_CNT);
    const unsigned* P0G = cnt + msl * 16;
    const unsigned* P1G = cnt + 64 + msl * 32;
    unsigned* myP0 = cnt + msl * 16 + nsl;
    int rawSeen = 0, warSeen = 0;
    const int tid = threadIdx.x;
    const int wave = tid >> 6, lane = tid & 63, lr = lane & 15, lq = lane >> 4;
    const int mg = wave >> 2, nw = wave & 3;
    const int colbase = nsl * 128 + nw * 32;

    const __hip_bfloat16* U0t = (const __hip_bfloat16*)(ws + OFF_U0T);
    const float* b0p = (const float*)(ws + OFF_B0P);
    const float* W0p = (const float*)(ws + OFF_W0P);
    __hip_bfloat16* h0b = (__hip_bfloat16*)(ws + OFF_H0B);

    // persistent B fragments, rotated: reg i holds logical k-chunk (nsl+i)&15
    short8 Bf[32];
#pragma unroll
    for (int i = 0; i < 16; ++i) {
        int l = (nsl + i) & 15;
        Bf[i]      = *(const short8*)(U0t + (size_t)(colbase + lr) * 512 + l * 32 + lq * 8);
        Bf[16 + i] = *(const short8*)(U0t + (size_t)(colbase + 16 + lr) * 512 + l * 32 + lq * 8);
    }

    const int cu = tid & 31, crb = tid >> 5;
    const int uu = nsl * 32 + cu;
    const int pcc = nsl * 128 + cu * 4;
    const float4v bias4 = *(const float4v*)(b0p + pcc);
    const float4v w0x = *(const float4v*)(W0p + pcc);
    const float4v w0y = *(const float4v*)(W0p + NG + pcc);
    const float4v w0z = *(const float4v*)(W0p + 2 * NG + pcc);
    const float tvi = 1.0f / tau0[uu], sv = s0v[uu];

    float c0r[8], h0r[8];
#pragma unroll
    for (int i = 0; i < 8; ++i) { c0r[i] = 0.0f; h0r[i] = 0.0f; }

    const int g_row = tid >> 2;
    const int g_q   = (tid & 3) ^ ((g_row >> 1) & 3);

    for (int s = 0; s < TDIM; ++s) {
        if (s >= 4) wait_min(P1G, 31, s - 3, warSeen);   // WAR, rarely binds
        wait_min(P0G, 15, s, rawSeen);                   // RAW, ~1 LLC load

        const __hip_bfloat16* Arow = h0b + ((size_t)((s + 3) & 3)) * HSLOT +
            (size_t)(msl * 128 + g_row) * 512 + g_q * 8;
        __hip_bfloat16* h0w = h0b + ((size_t)(s & 3)) * HSLOT;
        // prologue: tiles 0..5 (rotated) into slots 0..5
#pragma unroll
        for (int j = 0; j < 6; ++j)
            gload16(Arow + ((nsl + j) & 15) * 32, smem + j * 8192 + wave * 1024);

        const float4v z4 = {0.0f, 0.0f, 0.0f, 0.0f};
        float4v acc[4][2];
#pragma unroll
        for (int mf = 0; mf < 4; ++mf) { acc[mf][0] = z4; acc[mf][1] = z4; }

#pragma unroll
        for (int I = 0; I < 8; ++I) {
            asm volatile("s_waitcnt vmcnt(%0)" :: "i"((I <= 5) ? 4 : (14 - 2 * I)) : "memory");
            __builtin_amdgcn_s_barrier();
            __builtin_amdgcn_sched_barrier(0);
            if (I < 5) {
                int t0 = 2 * I + 6, t1 = 2 * I + 7;
                gload16(Arow + ((nsl + t0) & 15) * 32, smem + (t0 & 7) * 8192 + wave * 1024);
                gload16(Arow + ((nsl + t1) & 15) * 32, smem + (t1 & 7) * 8192 + wave * 1024);
            }
            const short* sA0 = (const short*)(smem + ((2 * I) & 7) * 8192);
            const short* sA1 = (const short*)(smem + ((2 * I + 1) & 7) * 8192);
            short8 aF0[4], aF1[4];
#pragma unroll
            for (int mf = 0; mf < 4; ++mf) {
                int row = mg * 64 + mf * 16 + lr;
                int q = lq ^ ((row >> 1) & 3);
                aF0[mf] = *(const short8*)(sA0 + row * 32 + q * 8);
                aF1[mf] = *(const short8*)(sA1 + row * 32 + q * 8);
            }
#pragma unroll
            for (int mf = 0; mf < 4; ++mf) {
                acc[mf][0] = __builtin_amdgcn_mfma_f32_16x16x32_bf16(aF0[mf], Bf[2 * I],          acc[mf][0], 0, 0, 0);
                acc[mf][1] = __builtin_amdgcn_mfma_f32_16x16x32_bf16(aF0[mf], Bf[16 + 2 * I],     acc[mf][1], 0, 0, 0);
                acc[mf][0] = __builtin_amdgcn_mfma_f32_16x16x32_bf16(aF1[mf], Bf[2 * I + 1],      acc[mf][0], 0, 0, 0);
                acc[mf][1] = __builtin_amdgcn_mfma_f32_16x16x32_bf16(aF1[mf], Bf[16 + 2 * I + 1], acc[mf][1], 0, 0, 0);
            }
        }
        __syncthreads();
        float* Z = (float*)smem;   // zone [64][132] f32, two passes (aliases ring)
#pragma unroll
        for (int pass = 0; pass < 2; ++pass) {
            if (mg == pass) {
#pragma unroll
                for (int mf = 0; mf < 4; ++mf)
#pragma unroll
                    for (int nf = 0; nf < 2; ++nf)
#pragma unroll
                        for (int i = 0; i < 4; ++i)
                            Z[(mf * 16 + lq * 4 + i) * 132 + nw * 32 + nf * 16 + lr] = acc[mf][nf][i];
            }
            __syncthreads();
#pragma unroll
            for (int cc = 0; cc < 4; ++cc) {
                int rl = crb + 16 * cc;
                int b = msl * 128 + pass * 64 + rl;
                float4v z = *(const float4v*)(Z + rl * 132 + cu * 4);
                const float* xp = inputs + ((size_t)b * TDIM + s) * 3;
                float x0 = xp[0], x1 = xp[1], x2 = xp[2];
                float zi = z[0] + bias4[0] + x0 * w0x[0] + x1 * w0y[0] + x2 * w0z[0];
                float zf = z[1] + bias4[1] + x0 * w0x[1] + x1 * w0y[1] + x2 * w0z[1];
                float zg = z[2] + bias4[2] + x0 * w0x[2] + x1 * w0y[2] + x2 * w0z[2];
                float zo = z[3] + bias4[3] + x0 * w0x[3] + x1 * w0y[3] + x2 * w0z[3];
                float tt = times[(size_t)b * TDIM + s];
                cell_update(zi, zf, zg, zo, tt, tvi, sv, c0r[pass * 4 + cc], h0r[pass * 4 + cc]);
                __hip_bfloat16 hb = __float2bfloat16(h0r[pass * 4 + cc]);
                store_u16_llc(h0w + (size_t)b * 512 + uu, *(unsigned short*)&hb);
            }
            __syncthreads();
        }
        if (tid == 0) store_cnt(myP0, (unsigned)(s + 1));   // single-writer signal
    }
}

// ---------------- layer 1: 128 blocks, tile 64 rows x 128 gate-cols, K=1024 split ----------------
// RAW h0[s-1]: min16(P0G[g]) >= s. RAW h1[s-2]: min16(P1G row m8) >= s-1.
// WAR (h1 slot, staged by FC@s-3): PF >= 4(s-4). Signals own P1G dword (=s).
__device__ void layer1_persist(char* smem, int blk,
    const float* __restrict__ times,
    const float* __restrict__ tau1, const float* __restrict__ s1v, char* __restrict__ ws)
{
    const int m8 = blk >> 4, nsl = blk & 15;
    const int grp = m8 >> 1, half = m8 & 1;
    unsigned* cnt = (unsigned*)(ws + OFF_CNT);
    const unsigned* P0G = cnt + grp * 16;
    const unsigned* P1R = cnt + 64 + grp * 32 + half * 16;
    unsigned* myP1 = cnt + 64 + grp * 32 + half * 16 + nsl;
    unsigned* PF = cnt + 192 + grp * 16;
    int raw0Seen = 0, raw1Seen = 0, pfSeen = 0;
    const int tid = threadIdx.x;
    const int wave = tid >> 6, lane = tid & 63, lr = lane & 15, lq = lane >> 4;
    const int kg = wave >> 2, nw = wave & 3;
    const int colbase = nsl * 128 + nw * 32;
    const int r1 = nsl & 7;

    const __hip_bfloat16* Wc = (const __hip_bfloat16*)(ws + OFF_W1U1T);
    const float* b1p = (const float*)(ws + OFF_B1P);
    __hip_bfloat16* h0b = (__hip_bfloat16*)(ws + OFF_H0B);
    __hip_bfloat16* h1b = (__hip_bfloat16*)(ws + OFF_H1B);
    float* h1f = (float*)(ws + OFF_H1F);

    // rotated: reg pair (i*2+kk) holds logical 64-wide chunk (i+r1)&7
    short8 Bf[32];
#pragma unroll
    for (int i = 0; i < 8; ++i) {
        int l = (i + r1) & 7;
#pragma unroll
        for (int kk = 0; kk < 2; ++kk) {
            Bf[i * 2 + kk]      = *(const short8*)(Wc + (size_t)(colbase + lr) * 1024 + kg * 512 + (l * 2 + kk) * 32 + lq * 8);
            Bf[16 + i * 2 + kk] = *(const short8*)(Wc + (size_t)(colbase + 16 + lr) * 1024 + kg * 512 + (l * 2 + kk) * 32 + lq * 8);
        }
    }

    const int cu = tid & 31, crb = tid >> 5;
    const int uu = nsl * 32 + cu;
    const int pcc = nsl * 128 + cu * 4;
    const float4v bias4 = *(const float4v*)(b1p + pcc);
    const float tvi = 1.0f / tau1[uu], sv = s1v[uu];

    float c1r[4], h1r[4];
#pragma unroll
    for (int i = 0; i < 4; ++i) { c1r[i] = 0.0f; h1r[i] = 0.0f; }

    const int g_row = tid >> 3;
    const int g_q   = (tid & 7) ^ (g_row & 7);

    for (int s = 1; s <= TDIM; ++s) {
        const int t = s - 1;
        if (s >= 5) wait_val(PF, 4 * (s - 4), pfSeen);   // WAR, value-cached
        wait_min(P0G, 15, s, raw0Seen);
        wait_min(P1R, 15, s - 1, raw1Seen);

        const __hip_bfloat16* A0 = h0b + ((size_t)((s + 3) & 3)) * HSLOT +
            (size_t)(m8 * 64 + g_row) * 512 + g_q * 8;
        const __hip_bfloat16* A1 = h1b + ((size_t)((s + 2) & 3)) * HSLOT +
            (size_t)(m8 * 64 + g_row) * 512 + g_q * 8;
        __hip_bfloat16* h1w = h1b + ((size_t)((s + 3) & 3)) * HSLOT;
        float* h1fw = h1f + ((size_t)((s + 3) & 3)) * FSLOT;
#pragma unroll
        for (int J = 0; J < 3; ++J) {
            int l = (J + r1) & 7;
            gload16(A0 + l * 64, smem + (J & 3) * 8192 + wave * 1024);
            gload16(A1 + l * 64, smem + 32768 + (J & 3) * 8192 + wave * 1024);
        }
        const float4v z4 = {0.0f, 0.0f, 0.0f, 0.0f};
        float4v acc[4][2];
#pragma unroll
        for (int mf = 0; mf < 4; ++mf) { acc[mf][0] = z4; acc[mf][1] = z4; }

#pragma unroll
        for (int J = 0; J < 8; ++J) {
            asm volatile("s_waitcnt vmcnt(%0)" :: "i"((J + 2 < 8) ? 4 : ((7 - J) * 2)) : "memory");
            __builtin_amdgcn_s_barrier();
            __builtin_amdgcn_sched_barrier(0);
            if (J + 3 < 8) {
                int l = (J + 3 + r1) & 7;
                gload16(A0 + l * 64, smem + ((J + 3) & 3) * 8192 + wave * 1024);
                gload16(A1 + l * 64, smem + 32768 + ((J + 3) & 3) * 8192 + wave * 1024);
            }
            const short* sA = (const short*)(smem + kg * 32768 + (J & 3) * 8192);
#pragma unroll
            for (int kk = 0; kk < 2; ++kk) {
                short8 aF[4];
#pragma unroll
                for (int mf = 0; mf < 4; ++mf) {
                    int row = mf * 16 + lr;
                    int q = (kk * 4 + lq) ^ (row & 7);
                    aF[mf] = *(const short8*)(sA + row * 64 + q * 8);
                }
#pragma unroll
                for (int mf = 0; mf < 4; ++mf) {
                    acc[mf][0] = __builtin_amdgcn_mfma_f32_16x16x32_bf16(aF[mf], Bf[J * 2 + kk],      acc[mf][0], 0, 0, 0);
                    acc[mf][1] = __builtin_amdgcn_mfma_f32_16x16x32_bf16(aF[mf], Bf[16 + J * 2 + kk], acc[mf][1], 0, 0, 0);
                }
            }
        }
        __syncthreads();
        float* Z = (float*)smem;   // zone [64][132] f32 (aliases rings)
        if (kg == 1) {
#pragma unroll
            for (int mf = 0; mf < 4; ++mf)
#pragma unroll
                for (int nf = 0; nf < 2; ++nf)
#pragma unroll
                    for (int i = 0; i < 4; ++i)
                        Z[(mf * 16 + lq * 4 + i) * 132 + nw * 32 + nf * 16 + lr] = acc[mf][nf][i];
        }
        __syncthreads();
        if (kg == 0) {
#pragma unroll
            for (int mf = 0; mf < 4; ++mf)
#pragma unroll
                for (int nf = 0; nf < 2; ++nf)
#pragma unroll
                    for (int i = 0; i < 4; ++i) {
                        int idx = (mf * 16 + lq * 4 + i) * 132 + nw * 32 + nf * 16 + lr;
                        Z[idx] += acc[mf][nf][i];
                    }
        }
        __syncthreads();
#pragma unroll
        for (int cc = 0; cc < 4; ++cc) {
            int rl = crb + 16 * cc;
            int b = m8 * 64 + rl;
            float4v z = *(const float4v*)(Z + rl * 132 + cu * 4);
            float zi = z[0] + bias4[0];
            float zf = z[1] + bias4[1];
            float zg = z[2] + bias4[2];
            float zo = z[3] + bias4[3];
            float tt = times[(size_t)b * TDIM + t];
            cell_update(zi, zf, zg, zo, tt, tvi, sv, c1r[cc], h1r[cc]);
            __hip_bfloat16 hb = __float2bfloat16(h1r[cc]);
            store_u16_llc(h1w + (size_t)b * 512 + uu, *(unsigned short*)&hb);
            store_f32_llc(h1fw + (size_t)b * 512 + uu, h1r[cc]);
        }
        __syncthreads();
        if (tid == 0) store_cnt(myP1, (unsigned)s);   // single-writer signal
    }
}

// ---------------- FC + softmax: 16 blocks x 32 rows ----------------
// RAW h1f[s-2]: min16(P1G row m8=blk>>1) >= s-1. Stages slice into LDS (SC1),
// signals PF right after staging (early ring release), computes from LDS.
__device__ void fc_persist(char* smem, int blk, const float* __restrict__ Wfc,
                           const float* __restrict__ bfc,
                           char* __restrict__ ws, float* __restrict__ out)
{
    const int grp = blk >> 2;
    unsigned* cnt = (unsigned*)(ws + OFF_CNT);
    const unsigned* P1R = cnt + 64 + grp * 32 + ((blk >> 1) & 1) * 16;
    unsigned* PF = cnt + 192 + grp * 16;
    int raw1Seen = 0;
    const int tid = threadIdx.x, wave = tid >> 6, lane = tid & 63;
    const float* h1f = (const float*)(ws + OFF_H1F);
    const int rbase = blk * 32;

    for (int s = 2; s <= TDIM + 1; ++s) {
        int t = s - 2;
        wait_min(P1R, 15, s - 1, raw1Seen);
        const char* h = (const char*)(h1f + ((size_t)((s + 2) & 3)) * FSLOT +
                                      (size_t)rbase * 512);
        // stage 32 rows x 512 f32 = 64KB: 8 chunks of 16B per thread
#pragma unroll
        for (int k = 0; k < 8; ++k)
            gload16(h + ((size_t)(tid + k * 512)) * 16, smem + k * 8192 + wave * 1024);
        asm volatile("s_waitcnt vmcnt(0)" ::: "memory");
        __syncthreads();
        if (tid == 0)
            __hip_atomic_fetch_add(PF, 1u, __ATOMIC_RELAXED, __HIP_MEMORY_SCOPE_AGENT);
        const float* hl = (const float*)smem;
        for (int ri = 0; ri < 4; ++ri) {
            int rl = wave * 4 + ri;
            int row = rbase + rl;
            float a[10];
#pragma unroll
            for (int c = 0; c < 10; ++c) a[c] = 0.0f;
#pragma unroll
            for (int itr = 0; itr < 8; ++itr) {
                float hv = hl[(size_t)rl * 512 + itr * 64 + lane];
                const float* wp = &Wfc[(size_t)(itr * 64 + lane) * 10];
#pragma unroll
                for (int c = 0; c < 10; ++c) a[c] += hv * wp[c];
            }
#pragma unroll
            for (int c = 0; c < 10; ++c)
                for (int m = 32; m; m >>= 1) a[c] += __shfl_xor(a[c], m, 64);
            if (lane == 0) {
                float mx = -1e30f;
#pragma unroll
                for (int c = 0; c < 10; ++c) { a[c] += bfc[c]; mx = fmaxf(mx, a[c]); }
                float sum = 0.0f;
#pragma unroll
                for (int c = 0; c < 10; ++c) { a[c] = __expf(a[c] - mx); sum += a[c]; }
                float inv = 1.0f / sum;
                float* op = &out[((size_t)row * TDIM + t) * 10];
#pragma unroll
                for (int c = 0; c < 10; ++c) op[c] = a[c] * inv;
            }
        }
        __syncthreads();
    }
}

// blocks 0-63: layer0   64-191: layer1   192-207: FC
// Sync: single-writer per-producer counters (sc0sc1 dword stores) + lane-parallel
// min-reduce waits. No RMW contention, no thread0 relay, no cache-maintenance.
__global__ __launch_bounds__(512, 2)
void persist_kernel(const float* __restrict__ inputs, const float* __restrict__ times,
                    const float* __restrict__ tau0, const float* __restrict__ s0v,
                    const float* __restrict__ tau1, const float* __restrict__ s1v,
                    const float* __restrict__ Wfc, const float* __restrict__ bfc,
                    char* __restrict__ ws, float* __restrict__ out)
{
    __shared__ __align__(16) char smem[65536];
    int blk = blockIdx.x;
    if (blk < 64)       layer0_persist(smem, blk, inputs, times, tau0, s0v, ws);
    else if (blk < 192) layer1_persist(smem, blk - 64, times, tau1, s1v, ws);
    else                fc_persist(smem, blk - 192, Wfc, bfc, ws, out);
}

extern "C" void kernel_launch(void* const* d_in, const int* in_sizes, int n_in,
                              void* d_out, int out_size, void* d_ws, size_t ws_size,
                              hipStream_t stream) {
    const float* inputs = (const float*)d_in[0];
    const float* times  = (const float*)d_in[1];
    const float* W0   = (const float*)d_in[2];
    const float* U0   = (const float*)d_in[3];
    const float* b0   = (const float*)d_in[4];
    const float* tau0 = (const float*)d_in[5];
    const float* s0   = (const float*)d_in[6];
    const float* W1   = (const float*)d_in[7];
    const float* U1   = (const float*)d_in[8];
    const float* b1   = (const float*)d_in[9];
    const float* tau1 = (const float*)d_in[10];
    const float* s1   = (const float*)d_in[11];
    const float* Wfc  = (const float*)d_in[12];
    const float* bfc  = (const float*)d_in[13];
    float* out = (float*)d_out;
    char* ws = (char*)d_ws;

    hipMemsetAsync(ws + OFF_STATE, 0, STATE_BYTES, stream);
    prep_kernel<<<(NG * 1024) / 256, 256, 0, stream>>>(W0, U0, b0, W1, U1, b1, ws);

    void* kargs[] = {(void*)&inputs, (void*)&times, (void*)&tau0, (void*)&s0,
                     (void*)&tau1, (void*)&s1, (void*)&Wfc, (void*)&bfc,
                     (void*)&ws, (void*)&out};
    hipLaunchCooperativeKernel((const void*)persist_kernel, dim3(NBLK), dim3(512),
                               kargs, 0, stream);
}